// Round 4
// baseline (949.922 us; speedup 1.0000x reference)
//
#include <hip/hip_runtime.h>

#define DIM 128
#define BN_EPS_F 1e-5f

typedef unsigned int u32;
typedef unsigned short u16;

__device__ __forceinline__ float bflo(u32 w) {
    union { u32 u; float f; } c; c.u = w << 16; return c.f;
}
__device__ __forceinline__ float bfhi(u32 w) {
    union { u32 u; float f; } c; c.u = w & 0xffff0000u; return c.f;
}
// pack two floats to bf16x2 with round-to-nearest-even
__device__ __forceinline__ u32 packbf(float x, float y) {
    union { float f; u32 u; } ax, ay; ax.f = x; ay.f = y;
    u32 xr = (ax.u + 0x7fffu + ((ax.u >> 16) & 1u)) >> 16;
    u32 yr = (ay.u + 0x7fffu + ((ay.u >> 16) & 1u)) >> 16;
    return xr | (yr << 16);
}

// ---------------- CSR build ----------------

__global__ void hist_kernel(const int* __restrict__ dst, int* __restrict__ counts, int E) {
    int i = blockIdx.x * blockDim.x + threadIdx.x;
    int base = i * 4;
    if (base + 3 < E) {
        int4 d = *(const int4*)(dst + base);
        atomicAdd(&counts[d.x], 1);
        atomicAdd(&counts[d.y], 1);
        atomicAdd(&counts[d.z], 1);
        atomicAdd(&counts[d.w], 1);
    } else {
        for (int e = base; e < E; e++) atomicAdd(&counts[dst[e]], 1);
    }
}

__global__ __launch_bounds__(1024) void scan_kernel(const int* __restrict__ counts,
                                                    int* __restrict__ rowptr, int n) {
    __shared__ int sums[1024];
    const int CH = 16;
    int t = threadIdx.x;
    int base = t * CH;
    int local[CH];
    int s = 0;
#pragma unroll
    for (int i = 0; i < CH; i++) {
        int idx = base + i;
        local[i] = s;
        if (idx < n) s += counts[idx];
    }
    sums[t] = s;
    __syncthreads();
    for (int off = 1; off < 1024; off <<= 1) {
        int v = (t >= off) ? sums[t - off] : 0;
        __syncthreads();
        sums[t] += v;
        __syncthreads();
    }
    int prev = (t > 0) ? sums[t - 1] : 0;
#pragma unroll
    for (int i = 0; i < CH; i++) {
        int idx = base + i;
        if (idx < n) rowptr[idx] = prev + local[i];
    }
    if (t == 1023) rowptr[n] = sums[1023];
}

// fill: pos = rowptr[d] + (--counts[d]); counts ends all-zero (counts[0] = ticket)
__global__ void fill_kernel(const int* __restrict__ src, const int* __restrict__ dst,
                            const int* __restrict__ rowptr, int* __restrict__ counts,
                            int* __restrict__ srcsorted, int E) {
    int i = blockIdx.x * blockDim.x + threadIdx.x;
    int base = i * 4;
    if (base + 3 < E) {
        int4 d = *(const int4*)(dst + base);
        int4 s = *(const int4*)(src + base);
        int c0 = atomicSub(&counts[d.x], 1);
        int c1 = atomicSub(&counts[d.y], 1);
        int c2 = atomicSub(&counts[d.z], 1);
        int c3 = atomicSub(&counts[d.w], 1);
        srcsorted[rowptr[d.x] + c0 - 1] = s.x;
        srcsorted[rowptr[d.y] + c1 - 1] = s.y;
        srcsorted[rowptr[d.z] + c2 - 1] = s.z;
        srcsorted[rowptr[d.w] + c3 - 1] = s.w;
    } else {
        for (int e = base; e < E; e++) {
            int d = dst[e];
            int c = atomicSub(&counts[d], 1);
            srcsorted[rowptr[d] + c - 1] = src[e];
        }
    }
}

// ---------------- fused affine(prev-BN) + GIN aggregate + stats + finalize ----------
// h_pre_out[d] = a*( hin[d] + sum_{s in in(d)} hin[s] ) + (1+deg)*b  (eps=0)
// hin: fp32 x (layer0) or bf16 h_pre of previous layer. hout: bf16.
// Stats of the ROUNDED bf16 output accumulate via LDS block-reduce -> 8-sliced
// global fp32 atomics; last block (ticket) computes ab for THIS layer and
// zeroes the slices for the next layer.
template <int IN_F32, int USE_AB>
__global__ __launch_bounds__(256) void gather_kernel(
    const float* __restrict__ hin_f, const u16* __restrict__ hin_b,
    u16* __restrict__ hout, const int* __restrict__ rowptr, const int* __restrict__ srcs,
    float* __restrict__ ab, float* __restrict__ gsum, float* __restrict__ gsq,
    int* __restrict__ ticket, const float* __restrict__ gamma,
    const float* __restrict__ beta, int n, float inv_n) {
    __shared__ float4 ls[4][32];
    __shared__ float4 lq[4][32];
    int tid = threadIdx.x;
    int wid = tid >> 6;
    int node = blockIdx.x * 4 + wid;
    int lane = tid & 63;
    int slot = lane >> 5;
    int quad = lane & 31;

    float4 a = {1.f, 1.f, 1.f, 1.f};
    float4 b = {0.f, 0.f, 0.f, 0.f};
    if (USE_AB) {
        a = *(const float4*)(ab + quad * 4);
        b = *(const float4*)(ab + DIM + quad * 4);
    }

    float4 rr = {0.f, 0.f, 0.f, 0.f};
    u32 w0 = 0, w1 = 0;
    if (node < n) {
        int start = rowptr[node];
        int end = rowptr[node + 1];
        float4 acc[8];
#pragma unroll
        for (int u = 0; u < 8; u++) acc[u] = make_float4(0.f, 0.f, 0.f, 0.f);

        int e = start + slot;
        if (IN_F32) {
            for (; e + 14 < end; e += 16) {
                int s[8];
#pragma unroll
                for (int u = 0; u < 8; u++) s[u] = srcs[e + 2 * u];
#pragma unroll
                for (int u = 0; u < 8; u++) {
                    const float4 v = *(const float4*)(hin_f + (size_t)s[u] * DIM + quad * 4);
                    acc[u].x += v.x; acc[u].y += v.y; acc[u].z += v.z; acc[u].w += v.w;
                }
            }
            for (; e < end; e += 2) {
                const float4 v = *(const float4*)(hin_f + (size_t)srcs[e] * DIM + quad * 4);
                acc[0].x += v.x; acc[0].y += v.y; acc[0].z += v.z; acc[0].w += v.w;
            }
        } else {
            for (; e + 14 < end; e += 16) {
                int s[8];
#pragma unroll
                for (int u = 0; u < 8; u++) s[u] = srcs[e + 2 * u];
#pragma unroll
                for (int u = 0; u < 8; u++) {
                    const uint2 v = *(const uint2*)(hin_b + (size_t)s[u] * DIM + quad * 4);
                    acc[u].x += bflo(v.x); acc[u].y += bfhi(v.x);
                    acc[u].z += bflo(v.y); acc[u].w += bfhi(v.y);
                }
            }
            for (; e < end; e += 2) {
                const uint2 v = *(const uint2*)(hin_b + (size_t)srcs[e] * DIM + quad * 4);
                acc[0].x += bflo(v.x); acc[0].y += bfhi(v.x);
                acc[0].z += bflo(v.y); acc[0].w += bfhi(v.y);
            }
        }
#pragma unroll
        for (int u = 4; u < 8; u++) {
            acc[u - 4].x += acc[u].x; acc[u - 4].y += acc[u].y;
            acc[u - 4].z += acc[u].z; acc[u - 4].w += acc[u].w;
        }
        float sx = (acc[0].x + acc[1].x) + (acc[2].x + acc[3].x);
        float sy = (acc[0].y + acc[1].y) + (acc[2].y + acc[3].y);
        float sz = (acc[0].z + acc[1].z) + (acc[2].z + acc[3].z);
        float sw = (acc[0].w + acc[1].w) + (acc[2].w + acc[3].w);
        sx += __shfl_xor(sx, 32);
        sy += __shfl_xor(sy, 32);
        sz += __shfl_xor(sz, 32);
        sw += __shfl_xor(sw, 32);

        float4 self;
        if (IN_F32) {
            self = *(const float4*)(hin_f + (size_t)node * DIM + quad * 4);
        } else {
            const uint2 v = *(const uint2*)(hin_b + (size_t)node * DIM + quad * 4);
            self = make_float4(bflo(v.x), bfhi(v.x), bflo(v.y), bfhi(v.y));
        }
        float degp1 = 1.0f + (float)(end - start);
        float4 r;
        r.x = a.x * (self.x + sx) + degp1 * b.x;
        r.y = a.y * (self.y + sy) + degp1 * b.y;
        r.z = a.z * (self.z + sz) + degp1 * b.z;
        r.w = a.w * (self.w + sw) + degp1 * b.w;
        w0 = packbf(r.x, r.y);
        w1 = packbf(r.z, r.w);
        rr = make_float4(bflo(w0), bfhi(w0), bflo(w1), bfhi(w1));
        if (slot == 0) {
            uint2 wv; wv.x = w0; wv.y = w1;
            *(uint2*)(hout + (size_t)node * DIM + quad * 4) = wv;
        }
    }
    // stats of rounded values: slot0 -> sums, slot1 -> squares
    if (slot == 0) ls[wid][quad] = rr;
    else lq[wid][quad] = make_float4(rr.x * rr.x, rr.y * rr.y, rr.z * rr.z, rr.w * rr.w);
    __syncthreads();
    int slice = (blockIdx.x & 7) * DIM;
    if (tid < 32) {
        float4 s0 = ls[0][tid], s1 = ls[1][tid], s2 = ls[2][tid], s3 = ls[3][tid];
        atomicAdd(&gsum[slice + tid * 4 + 0], (s0.x + s1.x) + (s2.x + s3.x));
        atomicAdd(&gsum[slice + tid * 4 + 1], (s0.y + s1.y) + (s2.y + s3.y));
        atomicAdd(&gsum[slice + tid * 4 + 2], (s0.z + s1.z) + (s2.z + s3.z));
        atomicAdd(&gsum[slice + tid * 4 + 3], (s0.w + s1.w) + (s2.w + s3.w));
    } else if (tid < 64) {
        int q = tid - 32;
        float4 s0 = lq[0][q], s1 = lq[1][q], s2 = lq[2][q], s3 = lq[3][q];
        atomicAdd(&gsq[slice + q * 4 + 0], (s0.x + s1.x) + (s2.x + s3.x));
        atomicAdd(&gsq[slice + q * 4 + 1], (s0.y + s1.y) + (s2.y + s3.y));
        atomicAdd(&gsq[slice + q * 4 + 2], (s0.z + s1.z) + (s2.z + s3.z));
        atomicAdd(&gsq[slice + q * 4 + 3], (s0.w + s1.w) + (s2.w + s3.w));
    }
    // last-block finalize: compute ab for THIS layer, zero slices for next
    __threadfence();
    __shared__ int lastflag;
    if (tid == 0) lastflag = (atomicAdd(ticket, 1) == (int)gridDim.x - 1) ? 1 : 0;
    __syncthreads();
    if (!lastflag) return;
    __threadfence();
    if (tid == 0) *ticket = 0;
    if (tid < DIM) {
        float s = 0.f, q = 0.f;
#pragma unroll
        for (int k = 0; k < 8; k++) {
            s += gsum[k * DIM + tid];
            q += gsq[k * DIM + tid];
        }
#pragma unroll
        for (int k = 0; k < 8; k++) {
            gsum[k * DIM + tid] = 0.f;
            gsq[k * DIM + tid] = 0.f;
        }
        float mu = s * inv_n;
        float var = q * inv_n - mu * mu;
        float av = gamma[tid] * rsqrtf(var + BN_EPS_F);
        ab[tid] = av;
        ab[DIM + tid] = beta[tid] - mu * av;
    }
}

// ---------------- final affine apply (layer 3) ----------------
__global__ void apply_kernel(const u16* __restrict__ hb, const float* __restrict__ ab,
                             float* __restrict__ out, int total4) {
    int i = blockIdx.x * blockDim.x + threadIdx.x;
    if (i < total4) {
        int quad = i & 31;
        uint2 w = *(const uint2*)(hb + (size_t)i * 4);
        const float4 a = *(const float4*)(ab + quad * 4);
        const float4 b = *(const float4*)(ab + DIM + quad * 4);
        float4 r;
        r.x = a.x * bflo(w.x) + b.x;
        r.y = a.y * bfhi(w.x) + b.y;
        r.z = a.z * bflo(w.y) + b.z;
        r.w = a.w * bfhi(w.y) + b.w;
        ((float4*)out)[i] = r;
    }
}

extern "C" void kernel_launch(void* const* d_in, const int* in_sizes, int n_in,
                              void* d_out, int out_size, void* d_ws, size_t ws_size,
                              hipStream_t stream) {
    const float* x = (const float*)d_in[0];
    const float* gamma = (const float*)d_in[1];
    const float* beta = (const float*)d_in[2];
    const int* src = (const int*)d_in[3];
    const int* dst = (const int*)d_in[4];
    float* out = (float*)d_out;

    const int n = in_sizes[0] / DIM;   // 10000
    const int E = in_sizes[3];         // 640000

    char* ws = (char*)d_ws;
    auto alloc = [&](size_t bytes) -> char* {
        char* p = ws;
        ws += (bytes + 255) / 256 * 256;
        return p;
    };
    int* rowptr = (int*)alloc((size_t)(n + 1) * 4);
    // counts + gsum + gsq contiguous -> one memset zeroes all three
    int* counts = (int*)alloc((size_t)(n + 2048) * 4);
    float* gsum = (float*)(counts + n);          // 8 slices x 128
    float* gsq = gsum + 8 * DIM;                 // 8 slices x 128
    int* srcsorted = (int*)alloc((size_t)E * 4);
    float* ab = (float*)alloc(2 * DIM * 4);
    u16* hb0 = (u16*)alloc((size_t)n * DIM * 2);
    u16* hb1 = (u16*)alloc((size_t)n * DIM * 2);

    hipMemsetAsync(counts, 0, (size_t)(n + 2048) * 4, stream);

    const int E4 = (E + 3) / 4;
    hist_kernel<<<(E4 + 255) / 256, 256, 0, stream>>>(dst, counts, E);
    scan_kernel<<<1, 1024, 0, stream>>>(counts, rowptr, n);
    fill_kernel<<<(E4 + 255) / 256, 256, 0, stream>>>(src, dst, rowptr, counts, srcsorted, E);
    // counts[] is now all zero -> counts[0] is the zeroed finalize ticket

    int* ticket = &counts[0];
    const int GB = (n + 3) / 4;  // 2500 blocks, wave per node
    const float inv_n = 1.0f / n;

    gather_kernel<1, 0><<<GB, 256, 0, stream>>>(x, nullptr, hb0, rowptr, srcsorted, ab,
                                                gsum, gsq, ticket, gamma + 0 * DIM,
                                                beta + 0 * DIM, n, inv_n);
    gather_kernel<0, 1><<<GB, 256, 0, stream>>>(nullptr, hb0, hb1, rowptr, srcsorted, ab,
                                                gsum, gsq, ticket, gamma + 1 * DIM,
                                                beta + 1 * DIM, n, inv_n);
    gather_kernel<0, 1><<<GB, 256, 0, stream>>>(nullptr, hb1, hb0, rowptr, srcsorted, ab,
                                                gsum, gsq, ticket, gamma + 2 * DIM,
                                                beta + 2 * DIM, n, inv_n);
    gather_kernel<0, 1><<<GB, 256, 0, stream>>>(nullptr, hb0, hb1, rowptr, srcsorted, ab,
                                                gsum, gsq, ticket, gamma + 3 * DIM,
                                                beta + 3 * DIM, n, inv_n);
    apply_kernel<<<((n * DIM / 4) + 255) / 256, 256, 0, stream>>>(hb1, ab, out, n * DIM / 4);
}

// Round 5
// 343.985 us; speedup vs baseline: 2.7615x; 2.7615x over previous
//
#include <hip/hip_runtime.h>

#define DIM 128
#define BN_EPS_F 1e-5f
#define NSLICE 16   // stat slices: spreads atomic contention; preamble reduces them

typedef unsigned int u32;
typedef unsigned short u16;

__device__ __forceinline__ float bflo(u32 w) {
    union { u32 u; float f; } c; c.u = w << 16; return c.f;
}
__device__ __forceinline__ float bfhi(u32 w) {
    union { u32 u; float f; } c; c.u = w & 0xffff0000u; return c.f;
}
// pack two floats to bf16x2 with round-to-nearest-even
__device__ __forceinline__ u32 packbf(float x, float y) {
    union { float f; u32 u; } ax, ay; ax.f = x; ay.f = y;
    u32 xr = (ax.u + 0x7fffu + ((ax.u >> 16) & 1u)) >> 16;
    u32 yr = (ay.u + 0x7fffu + ((ay.u >> 16) & 1u)) >> 16;
    return xr | (yr << 16);
}

// ---------------- CSR build ----------------

__global__ void hist_kernel(const int* __restrict__ dst, int* __restrict__ counts, int E) {
    int i = blockIdx.x * blockDim.x + threadIdx.x;
    int base = i * 4;
    if (base + 3 < E) {
        int4 d = *(const int4*)(dst + base);
        atomicAdd(&counts[d.x], 1);
        atomicAdd(&counts[d.y], 1);
        atomicAdd(&counts[d.z], 1);
        atomicAdd(&counts[d.w], 1);
    } else {
        for (int e = base; e < E; e++) atomicAdd(&counts[dst[e]], 1);
    }
}

__global__ __launch_bounds__(1024) void scan_kernel(const int* __restrict__ counts,
                                                    int* __restrict__ rowptr, int n) {
    __shared__ int sums[1024];
    const int CH = 16;
    int t = threadIdx.x;
    int base = t * CH;
    int local[CH];
    int s = 0;
#pragma unroll
    for (int i = 0; i < CH; i++) {
        int idx = base + i;
        local[i] = s;
        if (idx < n) s += counts[idx];
    }
    sums[t] = s;
    __syncthreads();
    for (int off = 1; off < 1024; off <<= 1) {
        int v = (t >= off) ? sums[t - off] : 0;
        __syncthreads();
        sums[t] += v;
        __syncthreads();
    }
    int prev = (t > 0) ? sums[t - 1] : 0;
#pragma unroll
    for (int i = 0; i < CH; i++) {
        int idx = base + i;
        if (idx < n) rowptr[idx] = prev + local[i];
    }
    if (t == 1023) rowptr[n] = sums[1023];
}

// fill: pos = rowptr[d] + (--counts[d]); counts ends all-zero
__global__ void fill_kernel(const int* __restrict__ src, const int* __restrict__ dst,
                            const int* __restrict__ rowptr, int* __restrict__ counts,
                            int* __restrict__ srcsorted, int E) {
    int i = blockIdx.x * blockDim.x + threadIdx.x;
    int base = i * 4;
    if (base + 3 < E) {
        int4 d = *(const int4*)(dst + base);
        int4 s = *(const int4*)(src + base);
        int c0 = atomicSub(&counts[d.x], 1);
        int c1 = atomicSub(&counts[d.y], 1);
        int c2 = atomicSub(&counts[d.z], 1);
        int c3 = atomicSub(&counts[d.w], 1);
        srcsorted[rowptr[d.x] + c0 - 1] = s.x;
        srcsorted[rowptr[d.y] + c1 - 1] = s.y;
        srcsorted[rowptr[d.z] + c2 - 1] = s.z;
        srcsorted[rowptr[d.w] + c3 - 1] = s.w;
    } else {
        for (int e = base; e < E; e++) {
            int d = dst[e];
            int c = atomicSub(&counts[d], 1);
            srcsorted[rowptr[d] + c - 1] = src[e];
        }
    }
}

// ---------------- fused affine(prev-BN) + GIN aggregate + stats ----------------
// Preamble (USE_AB): every block reduces the PREVIOUS layer's sliced stats
// (kernel boundary = free device-wide sync; no fences anywhere) and computes
// a,b into LDS. Deterministic -> identical in all blocks.
// Body: h_pre_out[d] = a*( hin[d] + sum_in hin[s] ) + (1+deg)*b ; bf16 store.
// Epilogue: block-reduce rounded outputs, fp32 atomics into THIS layer's slice.
template <int IN_F32, int USE_AB>
__global__ __launch_bounds__(256) void gather_kernel(
    const float* __restrict__ hin_f, const u16* __restrict__ hin_b,
    u16* __restrict__ hout, const int* __restrict__ rowptr, const int* __restrict__ srcs,
    const float* __restrict__ stats_in, float* __restrict__ stats_out,
    const float* __restrict__ gamma, const float* __restrict__ beta,
    int n, float inv_n) {
    __shared__ float ab_s[2 * DIM];
    __shared__ float part[2][DIM];
    __shared__ float4 ls[4][32];
    __shared__ float4 lq[4][32];
    int tid = threadIdx.x;
    int wid = tid >> 6;
    int node = blockIdx.x * 4 + wid;
    int lane = tid & 63;
    int slot = lane >> 5;
    int quad = lane & 31;

    if (USE_AB) {
        int c = tid & 127;
        int which = tid >> 7;  // 0 = sums, 1 = squares
        const float* basep = stats_in + which * NSLICE * DIM + c;
        float acc = 0.f;
#pragma unroll
        for (int k = 0; k < NSLICE; k++) acc += basep[k * DIM];
        part[which][c] = acc;
        __syncthreads();
        if (tid < DIM) {
            float mu = part[0][tid] * inv_n;
            float var = part[1][tid] * inv_n - mu * mu;
            float av = gamma[tid] * rsqrtf(var + BN_EPS_F);
            ab_s[tid] = av;
            ab_s[DIM + tid] = beta[tid] - mu * av;
        }
        __syncthreads();
    }

    float4 a = {1.f, 1.f, 1.f, 1.f};
    float4 b = {0.f, 0.f, 0.f, 0.f};
    if (USE_AB) {
        a = *(const float4*)(ab_s + quad * 4);
        b = *(const float4*)(ab_s + DIM + quad * 4);
    }

    float4 rr = {0.f, 0.f, 0.f, 0.f};
    if (node < n) {
        int start = rowptr[node];
        int end = rowptr[node + 1];
        float4 acc[8];
#pragma unroll
        for (int u = 0; u < 8; u++) acc[u] = make_float4(0.f, 0.f, 0.f, 0.f);

        int e = start + slot;
        if (IN_F32) {
            for (; e + 14 < end; e += 16) {
                int s[8];
#pragma unroll
                for (int u = 0; u < 8; u++) s[u] = srcs[e + 2 * u];
#pragma unroll
                for (int u = 0; u < 8; u++) {
                    const float4 v = *(const float4*)(hin_f + (size_t)s[u] * DIM + quad * 4);
                    acc[u].x += v.x; acc[u].y += v.y; acc[u].z += v.z; acc[u].w += v.w;
                }
            }
            for (; e < end; e += 2) {
                const float4 v = *(const float4*)(hin_f + (size_t)srcs[e] * DIM + quad * 4);
                acc[0].x += v.x; acc[0].y += v.y; acc[0].z += v.z; acc[0].w += v.w;
            }
        } else {
            for (; e + 14 < end; e += 16) {
                int s[8];
#pragma unroll
                for (int u = 0; u < 8; u++) s[u] = srcs[e + 2 * u];
#pragma unroll
                for (int u = 0; u < 8; u++) {
                    const uint2 v = *(const uint2*)(hin_b + (size_t)s[u] * DIM + quad * 4);
                    acc[u].x += bflo(v.x); acc[u].y += bfhi(v.x);
                    acc[u].z += bflo(v.y); acc[u].w += bfhi(v.y);
                }
            }
            for (; e < end; e += 2) {
                const uint2 v = *(const uint2*)(hin_b + (size_t)srcs[e] * DIM + quad * 4);
                acc[0].x += bflo(v.x); acc[0].y += bfhi(v.x);
                acc[0].z += bflo(v.y); acc[0].w += bfhi(v.y);
            }
        }
#pragma unroll
        for (int u = 4; u < 8; u++) {
            acc[u - 4].x += acc[u].x; acc[u - 4].y += acc[u].y;
            acc[u - 4].z += acc[u].z; acc[u - 4].w += acc[u].w;
        }
        float sx = (acc[0].x + acc[1].x) + (acc[2].x + acc[3].x);
        float sy = (acc[0].y + acc[1].y) + (acc[2].y + acc[3].y);
        float sz = (acc[0].z + acc[1].z) + (acc[2].z + acc[3].z);
        float sw = (acc[0].w + acc[1].w) + (acc[2].w + acc[3].w);
        sx += __shfl_xor(sx, 32);
        sy += __shfl_xor(sy, 32);
        sz += __shfl_xor(sz, 32);
        sw += __shfl_xor(sw, 32);

        float4 self;
        if (IN_F32) {
            self = *(const float4*)(hin_f + (size_t)node * DIM + quad * 4);
        } else {
            const uint2 v = *(const uint2*)(hin_b + (size_t)node * DIM + quad * 4);
            self = make_float4(bflo(v.x), bfhi(v.x), bflo(v.y), bfhi(v.y));
        }
        float degp1 = 1.0f + (float)(end - start);
        float4 r;
        r.x = a.x * (self.x + sx) + degp1 * b.x;
        r.y = a.y * (self.y + sy) + degp1 * b.y;
        r.z = a.z * (self.z + sz) + degp1 * b.z;
        r.w = a.w * (self.w + sw) + degp1 * b.w;
        u32 w0 = packbf(r.x, r.y);
        u32 w1 = packbf(r.z, r.w);
        rr = make_float4(bflo(w0), bfhi(w0), bflo(w1), bfhi(w1));
        if (slot == 0) {
            uint2 wv; wv.x = w0; wv.y = w1;
            *(uint2*)(hout + (size_t)node * DIM + quad * 4) = wv;
        }
    }
    // stats of rounded values: slot0 -> sums, slot1 -> squares
    __syncthreads();  // ls/lq reuse after preamble; also pre-write ordering
    if (slot == 0) ls[wid][quad] = rr;
    else lq[wid][quad] = make_float4(rr.x * rr.x, rr.y * rr.y, rr.z * rr.z, rr.w * rr.w);
    __syncthreads();
    int slice = (blockIdx.x & (NSLICE - 1)) * DIM;
    if (tid < 32) {
        float4 s0 = ls[0][tid], s1 = ls[1][tid], s2 = ls[2][tid], s3 = ls[3][tid];
        atomicAdd(&stats_out[slice + tid * 4 + 0], (s0.x + s1.x) + (s2.x + s3.x));
        atomicAdd(&stats_out[slice + tid * 4 + 1], (s0.y + s1.y) + (s2.y + s3.y));
        atomicAdd(&stats_out[slice + tid * 4 + 2], (s0.z + s1.z) + (s2.z + s3.z));
        atomicAdd(&stats_out[slice + tid * 4 + 3], (s0.w + s1.w) + (s2.w + s3.w));
    } else if (tid < 64) {
        int q = tid - 32;
        float* sq = stats_out + NSLICE * DIM;
        float4 s0 = lq[0][q], s1 = lq[1][q], s2 = lq[2][q], s3 = lq[3][q];
        atomicAdd(&sq[slice + q * 4 + 0], (s0.x + s1.x) + (s2.x + s3.x));
        atomicAdd(&sq[slice + q * 4 + 1], (s0.y + s1.y) + (s2.y + s3.y));
        atomicAdd(&sq[slice + q * 4 + 2], (s0.z + s1.z) + (s2.z + s3.z));
        atomicAdd(&sq[slice + q * 4 + 3], (s0.w + s1.w) + (s2.w + s3.w));
    }
}

// ---------------- final affine apply (layer 3) ----------------
__global__ __launch_bounds__(256) void apply_kernel(const u16* __restrict__ hb,
                                                    const float* __restrict__ stats_in,
                                                    const float* __restrict__ gamma,
                                                    const float* __restrict__ beta,
                                                    float* __restrict__ out, int total4,
                                                    float inv_n) {
    __shared__ float ab_s[2 * DIM];
    __shared__ float part[2][DIM];
    int tid = threadIdx.x;
    {
        int c = tid & 127;
        int which = tid >> 7;
        const float* basep = stats_in + which * NSLICE * DIM + c;
        float acc = 0.f;
#pragma unroll
        for (int k = 0; k < NSLICE; k++) acc += basep[k * DIM];
        part[which][c] = acc;
        __syncthreads();
        if (tid < DIM) {
            float mu = part[0][tid] * inv_n;
            float var = part[1][tid] * inv_n - mu * mu;
            float av = gamma[tid] * rsqrtf(var + BN_EPS_F);
            ab_s[tid] = av;
            ab_s[DIM + tid] = beta[tid] - mu * av;
        }
        __syncthreads();
    }
    for (int i = blockIdx.x * blockDim.x + tid; i < total4; i += gridDim.x * blockDim.x) {
        int quad = i & 31;
        uint2 w = *(const uint2*)(hb + (size_t)i * 4);
        const float4 a = *(const float4*)(ab_s + quad * 4);
        const float4 b = *(const float4*)(ab_s + DIM + quad * 4);
        float4 r;
        r.x = a.x * bflo(w.x) + b.x;
        r.y = a.y * bfhi(w.x) + b.y;
        r.z = a.z * bflo(w.y) + b.z;
        r.w = a.w * bfhi(w.y) + b.w;
        ((float4*)out)[i] = r;
    }
}

extern "C" void kernel_launch(void* const* d_in, const int* in_sizes, int n_in,
                              void* d_out, int out_size, void* d_ws, size_t ws_size,
                              hipStream_t stream) {
    const float* x = (const float*)d_in[0];
    const float* gamma = (const float*)d_in[1];
    const float* beta = (const float*)d_in[2];
    const int* src = (const int*)d_in[3];
    const int* dst = (const int*)d_in[4];
    float* out = (float*)d_out;

    const int n = in_sizes[0] / DIM;   // 10000
    const int E = in_sizes[3];         // 640000

    char* ws = (char*)d_ws;
    auto alloc = [&](size_t bytes) -> char* {
        char* p = ws;
        ws += (bytes + 255) / 256 * 256;
        return p;
    };
    const int STATS_PER_LAYER = 2 * NSLICE * DIM;           // sums + squares
    int* rowptr = (int*)alloc((size_t)(n + 1) * 4);
    // counts + gstats contiguous -> one memset zeroes both
    int* counts = (int*)alloc((size_t)(n + 4 * STATS_PER_LAYER) * 4);
    float* gstats = (float*)(counts + n);                   // [4][2][NSLICE][DIM]
    int* srcsorted = (int*)alloc((size_t)E * 4);
    u16* hb0 = (u16*)alloc((size_t)n * DIM * 2);
    u16* hb1 = (u16*)alloc((size_t)n * DIM * 2);

    hipMemsetAsync(counts, 0, (size_t)(n + 4 * STATS_PER_LAYER) * 4, stream);

    const int E4 = (E + 3) / 4;
    hist_kernel<<<(E4 + 255) / 256, 256, 0, stream>>>(dst, counts, E);
    scan_kernel<<<1, 1024, 0, stream>>>(counts, rowptr, n);
    fill_kernel<<<(E4 + 255) / 256, 256, 0, stream>>>(src, dst, rowptr, counts, srcsorted, E);

    const int GB = (n + 3) / 4;  // one 64-lane wave per node
    const float inv_n = 1.0f / n;
    float* st0 = gstats + 0 * STATS_PER_LAYER;
    float* st1 = gstats + 1 * STATS_PER_LAYER;
    float* st2 = gstats + 2 * STATS_PER_LAYER;
    float* st3 = gstats + 3 * STATS_PER_LAYER;

    gather_kernel<1, 0><<<GB, 256, 0, stream>>>(x, nullptr, hb0, rowptr, srcsorted,
                                                nullptr, st0, nullptr, nullptr, n, inv_n);
    gather_kernel<0, 1><<<GB, 256, 0, stream>>>(nullptr, hb0, hb1, rowptr, srcsorted,
                                                st0, st1, gamma + 0 * DIM, beta + 0 * DIM,
                                                n, inv_n);
    gather_kernel<0, 1><<<GB, 256, 0, stream>>>(nullptr, hb1, hb0, rowptr, srcsorted,
                                                st1, st2, gamma + 1 * DIM, beta + 1 * DIM,
                                                n, inv_n);
    gather_kernel<0, 1><<<GB, 256, 0, stream>>>(nullptr, hb0, hb1, rowptr, srcsorted,
                                                st2, st3, gamma + 2 * DIM, beta + 2 * DIM,
                                                n, inv_n);
    apply_kernel<<<256, 256, 0, stream>>>(hb1, st3, gamma + 3 * DIM, beta + 3 * DIM, out,
                                          n * DIM / 4, inv_n);
}

// Round 6
// 248.917 us; speedup vs baseline: 3.8162x; 1.3819x over previous
//
#include <hip/hip_runtime.h>

#define DIM 128
#define BN_EPS_F 1e-5f
#define NSLICE 16   // stat slices: spreads atomic contention; preamble reduces them

typedef unsigned int u32;
typedef unsigned short u16;

__device__ __forceinline__ float bflo(u32 w) {
    union { u32 u; float f; } c; c.u = w << 16; return c.f;
}
__device__ __forceinline__ float bfhi(u32 w) {
    union { u32 u; float f; } c; c.u = w & 0xffff0000u; return c.f;
}
// pack two floats to bf16x2 with round-to-nearest-even
__device__ __forceinline__ u32 packbf(float x, float y) {
    union { float f; u32 u; } ax, ay; ax.f = x; ay.f = y;
    u32 xr = (ax.u + 0x7fffu + ((ax.u >> 16) & 1u)) >> 16;
    u32 yr = (ay.u + 0x7fffu + ((ay.u >> 16) & 1u)) >> 16;
    return xr | (yr << 16);
}

// ---------------- CSR build ----------------

__global__ void hist_kernel(const int* __restrict__ dst, int* __restrict__ counts, int E) {
    int i = blockIdx.x * blockDim.x + threadIdx.x;
    int base = i * 4;
    if (base + 3 < E) {
        int4 d = *(const int4*)(dst + base);
        atomicAdd(&counts[d.x], 1);
        atomicAdd(&counts[d.y], 1);
        atomicAdd(&counts[d.z], 1);
        atomicAdd(&counts[d.w], 1);
    } else {
        for (int e = base; e < E; e++) atomicAdd(&counts[dst[e]], 1);
    }
}

__global__ __launch_bounds__(1024) void scan_kernel(const int* __restrict__ counts,
                                                    int* __restrict__ rowptr, int n) {
    __shared__ int sums[1024];
    const int CH = 16;
    int t = threadIdx.x;
    int base = t * CH;
    int local[CH];
    int s = 0;
#pragma unroll
    for (int i = 0; i < CH; i++) {
        int idx = base + i;
        local[i] = s;
        if (idx < n) s += counts[idx];
    }
    sums[t] = s;
    __syncthreads();
    for (int off = 1; off < 1024; off <<= 1) {
        int v = (t >= off) ? sums[t - off] : 0;
        __syncthreads();
        sums[t] += v;
        __syncthreads();
    }
    int prev = (t > 0) ? sums[t - 1] : 0;
#pragma unroll
    for (int i = 0; i < CH; i++) {
        int idx = base + i;
        if (idx < n) rowptr[idx] = prev + local[i];
    }
    if (t == 1023) rowptr[n] = sums[1023];
}

// fill: pos = rowptr[d] + (--counts[d]); counts ends all-zero
__global__ void fill_kernel(const int* __restrict__ src, const int* __restrict__ dst,
                            const int* __restrict__ rowptr, int* __restrict__ counts,
                            int* __restrict__ srcsorted, int E) {
    int i = blockIdx.x * blockDim.x + threadIdx.x;
    int base = i * 4;
    if (base + 3 < E) {
        int4 d = *(const int4*)(dst + base);
        int4 s = *(const int4*)(src + base);
        int c0 = atomicSub(&counts[d.x], 1);
        int c1 = atomicSub(&counts[d.y], 1);
        int c2 = atomicSub(&counts[d.z], 1);
        int c3 = atomicSub(&counts[d.w], 1);
        srcsorted[rowptr[d.x] + c0 - 1] = s.x;
        srcsorted[rowptr[d.y] + c1 - 1] = s.y;
        srcsorted[rowptr[d.z] + c2 - 1] = s.z;
        srcsorted[rowptr[d.w] + c3 - 1] = s.w;
    } else {
        for (int e = base; e < E; e++) {
            int d = dst[e];
            int c = atomicSub(&counts[d], 1);
            srcsorted[rowptr[d] + c - 1] = src[e];
        }
    }
}

// ---------------- fp32 -> bf16 convert (x table) ----------------
__global__ void cvt_kernel(const float* __restrict__ x, u16* __restrict__ xb, int total4) {
    int i = blockIdx.x * blockDim.x + threadIdx.x;
    if (i < total4) {
        float4 v = ((const float4*)x)[i];
        uint2 w;
        w.x = packbf(v.x, v.y);
        w.y = packbf(v.z, v.w);
        *(uint2*)(xb + (size_t)i * 4) = w;
    }
}

// ---------------- fused affine(prev-BN) + GIN aggregate + stats ----------------
// Preamble (USE_AB): every block reduces the PREVIOUS layer's sliced stats and
// computes a,b into LDS (kernel boundary = free device-wide sync; no fences).
// Body: one 64-lane wave per node; lane = grp(4) x sub(16). Each 16-lane group
// reads a FULL 256B bf16 row with one uint4 load -> 4 edges per wave-instr.
// Epilogue: block-reduce rounded outputs, fp32 atomics into THIS layer's slice.
template <int USE_AB>
__global__ __launch_bounds__(256) void gather_kernel(
    const u16* __restrict__ hin, u16* __restrict__ hout,
    const int* __restrict__ rowptr, const int* __restrict__ srcs,
    const float* __restrict__ stats_in, float* __restrict__ stats_out,
    const float* __restrict__ gamma, const float* __restrict__ beta,
    int n, float inv_n) {
    __shared__ float ab_s[2 * DIM];
    __shared__ float part[2][DIM];
    __shared__ float ls[4][DIM];
    __shared__ float lq[4][DIM];
    int tid = threadIdx.x;
    int wid = tid >> 6;
    int node = blockIdx.x * 4 + wid;
    int lane = tid & 63;
    int grp = lane >> 4;   // 0..3: which edge-slot
    int sub = lane & 15;   // 16 lanes x uint4 = 256B = one bf16 row

    if (USE_AB) {
        int c = tid & 127;
        int which = tid >> 7;  // 0 = sums, 1 = squares
        const float* basep = stats_in + which * NSLICE * DIM + c;
        float acc = 0.f;
#pragma unroll
        for (int k = 0; k < NSLICE; k++) acc += basep[k * DIM];
        part[which][c] = acc;
        __syncthreads();
        if (tid < DIM) {
            float mu = part[0][tid] * inv_n;
            float var = part[1][tid] * inv_n - mu * mu;
            float av = gamma[tid] * rsqrtf(var + BN_EPS_F);
            ab_s[tid] = av;
            ab_s[DIM + tid] = beta[tid] - mu * av;
        }
        __syncthreads();
    }

    float r[8];
#pragma unroll
    for (int k = 0; k < 8; k++) r[k] = 0.f;

    if (node < n) {
        int start = rowptr[node];
        int end = rowptr[node + 1];
        const u16* hsub = hin + sub * 8;
        float acc[8];
#pragma unroll
        for (int k = 0; k < 8; k++) acc[k] = 0.f;

        int eb = start;
        for (; eb + 16 <= end; eb += 16) {
            int e0 = eb + grp * 4;
            int s0 = srcs[e0 + 0];
            int s1 = srcs[e0 + 1];
            int s2 = srcs[e0 + 2];
            int s3 = srcs[e0 + 3];
            uint4 v0 = *(const uint4*)(hsub + (size_t)s0 * DIM);
            uint4 v1 = *(const uint4*)(hsub + (size_t)s1 * DIM);
            uint4 v2 = *(const uint4*)(hsub + (size_t)s2 * DIM);
            uint4 v3 = *(const uint4*)(hsub + (size_t)s3 * DIM);
            acc[0] += (bflo(v0.x) + bflo(v1.x)) + (bflo(v2.x) + bflo(v3.x));
            acc[1] += (bfhi(v0.x) + bfhi(v1.x)) + (bfhi(v2.x) + bfhi(v3.x));
            acc[2] += (bflo(v0.y) + bflo(v1.y)) + (bflo(v2.y) + bflo(v3.y));
            acc[3] += (bfhi(v0.y) + bfhi(v1.y)) + (bfhi(v2.y) + bfhi(v3.y));
            acc[4] += (bflo(v0.z) + bflo(v1.z)) + (bflo(v2.z) + bflo(v3.z));
            acc[5] += (bfhi(v0.z) + bfhi(v1.z)) + (bfhi(v2.z) + bfhi(v3.z));
            acc[6] += (bflo(v0.w) + bflo(v1.w)) + (bflo(v2.w) + bflo(v3.w));
            acc[7] += (bfhi(v0.w) + bfhi(v1.w)) + (bfhi(v2.w) + bfhi(v3.w));
        }
        for (int e = eb + grp; e < end; e += 4) {
            int s = srcs[e];
            uint4 v = *(const uint4*)(hsub + (size_t)s * DIM);
            acc[0] += bflo(v.x); acc[1] += bfhi(v.x);
            acc[2] += bflo(v.y); acc[3] += bfhi(v.y);
            acc[4] += bflo(v.z); acc[5] += bfhi(v.z);
            acc[6] += bflo(v.w); acc[7] += bfhi(v.w);
        }
        // reduce the 4 groups: lanes with same sub end up with the full sum
#pragma unroll
        for (int k = 0; k < 8; k++) {
            acc[k] += __shfl_xor(acc[k], 16);
            acc[k] += __shfl_xor(acc[k], 32);
        }

        uint4 sv = *(const uint4*)(hin + (size_t)node * DIM + sub * 8);
        float self[8] = {bflo(sv.x), bfhi(sv.x), bflo(sv.y), bfhi(sv.y),
                         bflo(sv.z), bfhi(sv.z), bflo(sv.w), bfhi(sv.w)};
        float degp1 = 1.0f + (float)(end - start);

        float av[8], bv[8];
        if (USE_AB) {
            float4 a0 = *(const float4*)(ab_s + sub * 8);
            float4 a1 = *(const float4*)(ab_s + sub * 8 + 4);
            float4 b0 = *(const float4*)(ab_s + DIM + sub * 8);
            float4 b1 = *(const float4*)(ab_s + DIM + sub * 8 + 4);
            av[0] = a0.x; av[1] = a0.y; av[2] = a0.z; av[3] = a0.w;
            av[4] = a1.x; av[5] = a1.y; av[6] = a1.z; av[7] = a1.w;
            bv[0] = b0.x; bv[1] = b0.y; bv[2] = b0.z; bv[3] = b0.w;
            bv[4] = b1.x; bv[5] = b1.y; bv[6] = b1.z; bv[7] = b1.w;
        } else {
#pragma unroll
            for (int k = 0; k < 8; k++) { av[k] = 1.f; bv[k] = 0.f; }
        }

        float o[8];
#pragma unroll
        for (int k = 0; k < 8; k++) o[k] = av[k] * (self[k] + acc[k]) + degp1 * bv[k];
        u32 w0 = packbf(o[0], o[1]);
        u32 w1 = packbf(o[2], o[3]);
        u32 w2 = packbf(o[4], o[5]);
        u32 w3 = packbf(o[6], o[7]);
        if (grp == 0) {
            uint4 wv; wv.x = w0; wv.y = w1; wv.z = w2; wv.w = w3;
            *(uint4*)(hout + (size_t)node * DIM + sub * 8) = wv;
        }
        r[0] = bflo(w0); r[1] = bfhi(w0); r[2] = bflo(w1); r[3] = bfhi(w1);
        r[4] = bflo(w2); r[5] = bfhi(w2); r[6] = bflo(w3); r[7] = bfhi(w3);
    }

    // stats of rounded values (grp 0 holds the final r for its node; zeros if node>=n)
    if (grp == 0) {
#pragma unroll
        for (int k = 0; k < 8; k++) {
            ls[wid][sub * 8 + k] = r[k];
            lq[wid][sub * 8 + k] = r[k] * r[k];
        }
    }
    __syncthreads();
    int slice = (blockIdx.x & (NSLICE - 1)) * DIM;
    int c = tid & 127;
    int which = tid >> 7;
    float s = which ? ((lq[0][c] + lq[1][c]) + (lq[2][c] + lq[3][c]))
                    : ((ls[0][c] + ls[1][c]) + (ls[2][c] + ls[3][c]));
    atomicAdd(&stats_out[which * NSLICE * DIM + slice + c], s);
}

// ---------------- final affine apply (layer 3) ----------------
__global__ __launch_bounds__(256) void apply_kernel(const u16* __restrict__ hb,
                                                    const float* __restrict__ stats_in,
                                                    const float* __restrict__ gamma,
                                                    const float* __restrict__ beta,
                                                    float* __restrict__ out, int total4,
                                                    float inv_n) {
    __shared__ float ab_s[2 * DIM];
    __shared__ float part[2][DIM];
    int tid = threadIdx.x;
    {
        int c = tid & 127;
        int which = tid >> 7;
        const float* basep = stats_in + which * NSLICE * DIM + c;
        float acc = 0.f;
#pragma unroll
        for (int k = 0; k < NSLICE; k++) acc += basep[k * DIM];
        part[which][c] = acc;
        __syncthreads();
        if (tid < DIM) {
            float mu = part[0][tid] * inv_n;
            float var = part[1][tid] * inv_n - mu * mu;
            float av = gamma[tid] * rsqrtf(var + BN_EPS_F);
            ab_s[tid] = av;
            ab_s[DIM + tid] = beta[tid] - mu * av;
        }
        __syncthreads();
    }
    for (int i = blockIdx.x * blockDim.x + tid; i < total4; i += gridDim.x * blockDim.x) {
        int quad = i & 31;
        uint2 w = *(const uint2*)(hb + (size_t)i * 4);
        const float4 a = *(const float4*)(ab_s + quad * 4);
        const float4 b = *(const float4*)(ab_s + DIM + quad * 4);
        float4 r;
        r.x = a.x * bflo(w.x) + b.x;
        r.y = a.y * bfhi(w.x) + b.y;
        r.z = a.z * bflo(w.y) + b.z;
        r.w = a.w * bfhi(w.y) + b.w;
        ((float4*)out)[i] = r;
    }
}

extern "C" void kernel_launch(void* const* d_in, const int* in_sizes, int n_in,
                              void* d_out, int out_size, void* d_ws, size_t ws_size,
                              hipStream_t stream) {
    const float* x = (const float*)d_in[0];
    const float* gamma = (const float*)d_in[1];
    const float* beta = (const float*)d_in[2];
    const int* src = (const int*)d_in[3];
    const int* dst = (const int*)d_in[4];
    float* out = (float*)d_out;

    const int n = in_sizes[0] / DIM;   // 10000
    const int E = in_sizes[3];         // 640000

    char* ws = (char*)d_ws;
    auto alloc = [&](size_t bytes) -> char* {
        char* p = ws;
        ws += (bytes + 255) / 256 * 256;
        return p;
    };
    const int STATS_PER_LAYER = 2 * NSLICE * DIM;           // sums + squares
    int* rowptr = (int*)alloc((size_t)(n + 1) * 4);
    // counts + gstats contiguous -> one memset zeroes both
    int* counts = (int*)alloc((size_t)(n + 4 * STATS_PER_LAYER) * 4);
    float* gstats = (float*)(counts + n);                   // [4][2][NSLICE][DIM]
    int* srcsorted = (int*)alloc((size_t)E * 4);
    u16* hbx = (u16*)alloc((size_t)n * DIM * 2);
    u16* hb0 = (u16*)alloc((size_t)n * DIM * 2);
    u16* hb1 = (u16*)alloc((size_t)n * DIM * 2);

    hipMemsetAsync(counts, 0, (size_t)(n + 4 * STATS_PER_LAYER) * 4, stream);

    const int E4 = (E + 3) / 4;
    hist_kernel<<<(E4 + 255) / 256, 256, 0, stream>>>(dst, counts, E);
    scan_kernel<<<1, 1024, 0, stream>>>(counts, rowptr, n);
    fill_kernel<<<(E4 + 255) / 256, 256, 0, stream>>>(src, dst, rowptr, counts, srcsorted, E);
    cvt_kernel<<<((n * DIM / 4) + 255) / 256, 256, 0, stream>>>(x, hbx, n * DIM / 4);

    const int GB = (n + 3) / 4;  // one 64-lane wave per node
    const float inv_n = 1.0f / n;
    float* st0 = gstats + 0 * STATS_PER_LAYER;
    float* st1 = gstats + 1 * STATS_PER_LAYER;
    float* st2 = gstats + 2 * STATS_PER_LAYER;
    float* st3 = gstats + 3 * STATS_PER_LAYER;

    gather_kernel<0><<<GB, 256, 0, stream>>>(hbx, hb0, rowptr, srcsorted,
                                             nullptr, st0, nullptr, nullptr, n, inv_n);
    gather_kernel<1><<<GB, 256, 0, stream>>>(hb0, hb1, rowptr, srcsorted,
                                             st0, st1, gamma + 0 * DIM, beta + 0 * DIM,
                                             n, inv_n);
    gather_kernel<1><<<GB, 256, 0, stream>>>(hb1, hb0, rowptr, srcsorted,
                                             st1, st2, gamma + 1 * DIM, beta + 1 * DIM,
                                             n, inv_n);
    gather_kernel<1><<<GB, 256, 0, stream>>>(hb0, hb1, rowptr, srcsorted,
                                             st2, st3, gamma + 2 * DIM, beta + 2 * DIM,
                                             n, inv_n);
    apply_kernel<<<256, 256, 0, stream>>>(hb1, st3, gamma + 3 * DIM, beta + 3 * DIM, out,
                                          n * DIM / 4, inv_n);
}

// Round 7
// 212.564 us; speedup vs baseline: 4.4689x; 1.1710x over previous
//
#include <hip/hip_runtime.h>

#define DIM 128
#define BN_EPS_F 1e-5f
#define NSLICE 16   // stat slices: spreads atomic contention; preamble reduces them
#define MAXN 10240  // LDS histogram capacity (n = 10000)
#define CHUNKS 256  // edge chunks == blocks in chunkhist/scatter

typedef unsigned int u32;
typedef unsigned short u16;

__device__ __forceinline__ float bflo(u32 w) {
    union { u32 u; float f; } c; c.u = w << 16; return c.f;
}
__device__ __forceinline__ float bfhi(u32 w) {
    union { u32 u; float f; } c; c.u = w & 0xffff0000u; return c.f;
}
// pack two floats to bf16x2 with round-to-nearest-even
__device__ __forceinline__ u32 packbf(float x, float y) {
    union { float f; u32 u; } ax, ay; ax.f = x; ay.f = y;
    u32 xr = (ax.u + 0x7fffu + ((ax.u >> 16) & 1u)) >> 16;
    u32 yr = (ay.u + 0x7fffu + ((ay.u >> 16) & 1u)) >> 16;
    return xr | (yr << 16);
}

// ---------------- CSR build (atomic-free counting sort) ----------------

// A: per-chunk private LDS histogram -> hist[chunk][bin]
__global__ __launch_bounds__(256) void chunkhist_kernel(const int* __restrict__ dst,
                                                        int* __restrict__ hist,
                                                        int n, int E, int chunk) {
    __shared__ int bins[MAXN];
    int tid = threadIdx.x;
    for (int i = tid; i < n; i += 256) bins[i] = 0;
    __syncthreads();
    int e0 = blockIdx.x * chunk;
    int e1 = min(e0 + chunk, E);
    for (int e = e0 + tid; e < e1; e += 256) atomicAdd(&bins[dst[e]], 1);
    __syncthreads();
    int* out = hist + (size_t)blockIdx.x * n;
    for (int i = tid; i < n; i += 256) out[i] = bins[i];
}

// B1: per-bin exclusive prefix over chunks; counts[bin] = total degree
__global__ __launch_bounds__(256) void chunkscan_kernel(const int* __restrict__ hist,
                                                        int* __restrict__ chunkpref,
                                                        int* __restrict__ counts, int n) {
    int bin = blockIdx.x * 256 + threadIdx.x;
    if (bin >= n) return;
    const int* hp = hist + bin;
    int* cp = chunkpref + bin;
    int run = 0;
#pragma unroll 32
    for (int b = 0; b < CHUNKS; b++) {
        int v = hp[(size_t)b * n];
        cp[(size_t)b * n] = run;
        run += v;
    }
    counts[bin] = run;
}

// B2: exclusive scan of 16-PADDED counts -> prowptr; fill pad slots with dummy n
__global__ __launch_bounds__(1024) void scan_kernel(const int* __restrict__ counts,
                                                    int* __restrict__ prowptr,
                                                    int* __restrict__ srcsorted, int n) {
    __shared__ int sums[1024];
    const int CH = 16;
    int t = threadIdx.x;
    int base = t * CH;
    int local[CH];
    int s = 0;
#pragma unroll
    for (int i = 0; i < CH; i++) {
        int idx = base + i;
        local[i] = s;
        if (idx < n) s += (counts[idx] + 15) & ~15;
    }
    sums[t] = s;
    __syncthreads();
    for (int off = 1; off < 1024; off <<= 1) {
        int v = (t >= off) ? sums[t - off] : 0;
        __syncthreads();
        sums[t] += v;
        __syncthreads();
    }
    int prev = (t > 0) ? sums[t - 1] : 0;
#pragma unroll
    for (int i = 0; i < CH; i++) {
        int idx = base + i;
        if (idx < n) {
            int pstart = prev + local[i];
            prowptr[idx] = pstart;
            int c = counts[idx];
            int p = (c + 15) & ~15;
            for (int k = c; k < p; k++) srcsorted[pstart + k] = n;  // dummy -> zero row
        }
    }
    if (t == 1023) prowptr[n] = sums[1023];
}

// C: scatter via LDS-ranked positions (no global atomics)
__global__ __launch_bounds__(256) void scatter_kernel(const int* __restrict__ src,
                                                      const int* __restrict__ dst,
                                                      const int* __restrict__ prowptr,
                                                      const int* __restrict__ chunkpref,
                                                      int* __restrict__ srcsorted,
                                                      int n, int E, int chunk) {
    __shared__ int cur[MAXN];
    int tid = threadIdx.x;
    const int* cp = chunkpref + (size_t)blockIdx.x * n;
    for (int i = tid; i < n; i += 256) cur[i] = prowptr[i] + cp[i];
    __syncthreads();
    int e0 = blockIdx.x * chunk;
    int e1 = min(e0 + chunk, E);
    for (int e = e0 + tid; e < e1; e += 256) {
        int d = dst[e];
        int pos = atomicAdd(&cur[d], 1);
        srcsorted[pos] = src[e];
    }
}

// ---------------- fp32 -> bf16 convert (x table) + zero dummy rows ----------------
__global__ void cvt_kernel(const float* __restrict__ x, u16* __restrict__ xb,
                           u16* __restrict__ r0, u16* __restrict__ r1, int total4, int n) {
    int i = blockIdx.x * blockDim.x + threadIdx.x;
    if (i < total4) {
        float4 v = ((const float4*)x)[i];
        uint2 w;
        w.x = packbf(v.x, v.y);
        w.y = packbf(v.z, v.w);
        *(uint2*)(xb + (size_t)i * 4) = w;
    } else {
        int j = i - total4;
        if (j < 96) {
            u16* t = (j < 32) ? xb : ((j < 64) ? r0 : r1);
            uint2 z; z.x = 0; z.y = 0;
            *(uint2*)(t + (size_t)n * DIM + (j & 31) * 4) = z;
        }
    }
}

// ---------------- fused affine(prev-BN) + GIN aggregate + stats ----------------
// Preamble (USE_AB): every block reduces the PREVIOUS layer's sliced stats and
// computes a,b into LDS (kernel boundary = free device-wide sync; no fences).
// Body: one 64-lane wave per node; lane = grp(4) x sub(16). Each 16-lane group
// reads a FULL 256B bf16 row with one uint4 load -> 4 edges per wave-instr.
// Edge lists are 16-padded with dummy node n (zero row) -> NO tail loop.
// Epilogue: block-reduce rounded outputs, fp32 atomics into THIS layer's slice.
template <int USE_AB>
__global__ __launch_bounds__(256) void gather_kernel(
    const u16* __restrict__ hin, u16* __restrict__ hout,
    const int* __restrict__ prowptr, const int* __restrict__ counts,
    const int* __restrict__ srcs,
    const float* __restrict__ stats_in, float* __restrict__ stats_out,
    const float* __restrict__ gamma, const float* __restrict__ beta,
    int n, float inv_n) {
    __shared__ float ab_s[2 * DIM];
    __shared__ float part[2][DIM];
    __shared__ float ls[4][DIM];
    __shared__ float lq[4][DIM];
    int tid = threadIdx.x;
    int wid = tid >> 6;
    int node = blockIdx.x * 4 + wid;
    int lane = tid & 63;
    int grp = lane >> 4;   // 0..3: which edge-slot
    int sub = lane & 15;   // 16 lanes x uint4 = 256B = one bf16 row

    if (USE_AB) {
        int c = tid & 127;
        int which = tid >> 7;  // 0 = sums, 1 = squares
        const float* basep = stats_in + which * NSLICE * DIM + c;
        float acc = 0.f;
#pragma unroll
        for (int k = 0; k < NSLICE; k++) acc += basep[k * DIM];
        part[which][c] = acc;
        __syncthreads();
        if (tid < DIM) {
            float mu = part[0][tid] * inv_n;
            float var = part[1][tid] * inv_n - mu * mu;
            float av = gamma[tid] * rsqrtf(var + BN_EPS_F);
            ab_s[tid] = av;
            ab_s[DIM + tid] = beta[tid] - mu * av;
        }
        __syncthreads();
    }

    float r[8];
#pragma unroll
    for (int k = 0; k < 8; k++) r[k] = 0.f;

    if (node < n) {
        int start = prowptr[node];
        int pend = prowptr[node + 1];
        int deg = counts[node];
        const u16* hsub = hin + sub * 8;
        float acc[8];
#pragma unroll
        for (int k = 0; k < 8; k++) acc[k] = 0.f;

        for (int eb = start; eb < pend; eb += 16) {
            int e0 = eb + grp * 4;
            int s0 = srcs[e0 + 0];
            int s1 = srcs[e0 + 1];
            int s2 = srcs[e0 + 2];
            int s3 = srcs[e0 + 3];
            uint4 v0 = *(const uint4*)(hsub + (size_t)s0 * DIM);
            uint4 v1 = *(const uint4*)(hsub + (size_t)s1 * DIM);
            uint4 v2 = *(const uint4*)(hsub + (size_t)s2 * DIM);
            uint4 v3 = *(const uint4*)(hsub + (size_t)s3 * DIM);
            acc[0] += (bflo(v0.x) + bflo(v1.x)) + (bflo(v2.x) + bflo(v3.x));
            acc[1] += (bfhi(v0.x) + bfhi(v1.x)) + (bfhi(v2.x) + bfhi(v3.x));
            acc[2] += (bflo(v0.y) + bflo(v1.y)) + (bflo(v2.y) + bflo(v3.y));
            acc[3] += (bfhi(v0.y) + bfhi(v1.y)) + (bfhi(v2.y) + bfhi(v3.y));
            acc[4] += (bflo(v0.z) + bflo(v1.z)) + (bflo(v2.z) + bflo(v3.z));
            acc[5] += (bfhi(v0.z) + bfhi(v1.z)) + (bfhi(v2.z) + bfhi(v3.z));
            acc[6] += (bflo(v0.w) + bflo(v1.w)) + (bflo(v2.w) + bflo(v3.w));
            acc[7] += (bfhi(v0.w) + bfhi(v1.w)) + (bfhi(v2.w) + bfhi(v3.w));
        }
        // reduce the 4 groups: lanes with same sub end up with the full sum
#pragma unroll
        for (int k = 0; k < 8; k++) {
            acc[k] += __shfl_xor(acc[k], 16);
            acc[k] += __shfl_xor(acc[k], 32);
        }

        uint4 sv = *(const uint4*)(hin + (size_t)node * DIM + sub * 8);
        float self[8] = {bflo(sv.x), bfhi(sv.x), bflo(sv.y), bfhi(sv.y),
                         bflo(sv.z), bfhi(sv.z), bflo(sv.w), bfhi(sv.w)};
        float degp1 = 1.0f + (float)deg;

        float av[8], bv[8];
        if (USE_AB) {
            float4 a0 = *(const float4*)(ab_s + sub * 8);
            float4 a1 = *(const float4*)(ab_s + sub * 8 + 4);
            float4 b0 = *(const float4*)(ab_s + DIM + sub * 8);
            float4 b1 = *(const float4*)(ab_s + DIM + sub * 8 + 4);
            av[0] = a0.x; av[1] = a0.y; av[2] = a0.z; av[3] = a0.w;
            av[4] = a1.x; av[5] = a1.y; av[6] = a1.z; av[7] = a1.w;
            bv[0] = b0.x; bv[1] = b0.y; bv[2] = b0.z; bv[3] = b0.w;
            bv[4] = b1.x; bv[5] = b1.y; bv[6] = b1.z; bv[7] = b1.w;
        } else {
#pragma unroll
            for (int k = 0; k < 8; k++) { av[k] = 1.f; bv[k] = 0.f; }
        }

        float o[8];
#pragma unroll
        for (int k = 0; k < 8; k++) o[k] = av[k] * (self[k] + acc[k]) + degp1 * bv[k];
        u32 w0 = packbf(o[0], o[1]);
        u32 w1 = packbf(o[2], o[3]);
        u32 w2 = packbf(o[4], o[5]);
        u32 w3 = packbf(o[6], o[7]);
        if (grp == 0) {
            uint4 wv; wv.x = w0; wv.y = w1; wv.z = w2; wv.w = w3;
            *(uint4*)(hout + (size_t)node * DIM + sub * 8) = wv;
        }
        r[0] = bflo(w0); r[1] = bfhi(w0); r[2] = bflo(w1); r[3] = bfhi(w1);
        r[4] = bflo(w2); r[5] = bfhi(w2); r[6] = bflo(w3); r[7] = bfhi(w3);
    }

    // stats of rounded values (grp 0 holds the final r for its node; zeros if node>=n)
    if (grp == 0) {
#pragma unroll
        for (int k = 0; k < 8; k++) {
            ls[wid][sub * 8 + k] = r[k];
            lq[wid][sub * 8 + k] = r[k] * r[k];
        }
    }
    __syncthreads();
    int slice = (blockIdx.x & (NSLICE - 1)) * DIM;
    int c = tid & 127;
    int which = tid >> 7;
    float s = which ? ((lq[0][c] + lq[1][c]) + (lq[2][c] + lq[3][c]))
                    : ((ls[0][c] + ls[1][c]) + (ls[2][c] + ls[3][c]));
    atomicAdd(&stats_out[which * NSLICE * DIM + slice + c], s);
}

// ---------------- final affine apply (layer 3) ----------------
__global__ __launch_bounds__(256) void apply_kernel(const u16* __restrict__ hb,
                                                    const float* __restrict__ stats_in,
                                                    const float* __restrict__ gamma,
                                                    const float* __restrict__ beta,
                                                    float* __restrict__ out, int total4,
                                                    float inv_n) {
    __shared__ float ab_s[2 * DIM];
    __shared__ float part[2][DIM];
    int tid = threadIdx.x;
    {
        int c = tid & 127;
        int which = tid >> 7;
        const float* basep = stats_in + which * NSLICE * DIM + c;
        float acc = 0.f;
#pragma unroll
        for (int k = 0; k < NSLICE; k++) acc += basep[k * DIM];
        part[which][c] = acc;
        __syncthreads();
        if (tid < DIM) {
            float mu = part[0][tid] * inv_n;
            float var = part[1][tid] * inv_n - mu * mu;
            float av = gamma[tid] * rsqrtf(var + BN_EPS_F);
            ab_s[tid] = av;
            ab_s[DIM + tid] = beta[tid] - mu * av;
        }
        __syncthreads();
    }
    for (int i = blockIdx.x * blockDim.x + tid; i < total4; i += gridDim.x * blockDim.x) {
        int quad = i & 31;
        uint2 w = *(const uint2*)(hb + (size_t)i * 4);
        const float4 a = *(const float4*)(ab_s + quad * 4);
        const float4 b = *(const float4*)(ab_s + DIM + quad * 4);
        float4 r;
        r.x = a.x * bflo(w.x) + b.x;
        r.y = a.y * bfhi(w.x) + b.y;
        r.z = a.z * bflo(w.y) + b.z;
        r.w = a.w * bfhi(w.y) + b.w;
        ((float4*)out)[i] = r;
    }
}

extern "C" void kernel_launch(void* const* d_in, const int* in_sizes, int n_in,
                              void* d_out, int out_size, void* d_ws, size_t ws_size,
                              hipStream_t stream) {
    const float* x = (const float*)d_in[0];
    const float* gamma = (const float*)d_in[1];
    const float* beta = (const float*)d_in[2];
    const int* src = (const int*)d_in[3];
    const int* dst = (const int*)d_in[4];
    float* out = (float*)d_out;

    const int n = in_sizes[0] / DIM;   // 10000
    const int E = in_sizes[3];         // 640000

    char* ws = (char*)d_ws;
    auto alloc = [&](size_t bytes) -> char* {
        char* p = ws;
        ws += (bytes + 255) / 256 * 256;
        return p;
    };
    const int STATS_PER_LAYER = 2 * NSLICE * DIM;                 // sums + squares
    int* prowptr = (int*)alloc((size_t)(n + 1) * 4);
    int* counts = (int*)alloc((size_t)n * 4);
    float* gstats = (float*)alloc((size_t)4 * STATS_PER_LAYER * 4);  // zeroed
    int* hist = (int*)alloc((size_t)CHUNKS * n * 4);
    int* chunkpref = (int*)alloc((size_t)CHUNKS * n * 4);
    int* srcsorted = (int*)alloc((size_t)(E + 16 * n) * 4);       // padded
    u16* hbx = (u16*)alloc((size_t)(n + 1) * DIM * 2);
    u16* hb0 = (u16*)alloc((size_t)(n + 1) * DIM * 2);
    u16* hb1 = (u16*)alloc((size_t)(n + 1) * DIM * 2);

    hipMemsetAsync(gstats, 0, (size_t)4 * STATS_PER_LAYER * 4, stream);

    const int chunk = (E + CHUNKS - 1) / CHUNKS;
    chunkhist_kernel<<<CHUNKS, 256, 0, stream>>>(dst, hist, n, E, chunk);
    chunkscan_kernel<<<(n + 255) / 256, 256, 0, stream>>>(hist, chunkpref, counts, n);
    scan_kernel<<<1, 1024, 0, stream>>>(counts, prowptr, srcsorted, n);
    scatter_kernel<<<CHUNKS, 256, 0, stream>>>(src, dst, prowptr, chunkpref, srcsorted,
                                               n, E, chunk);
    const int total4 = n * DIM / 4;
    cvt_kernel<<<(total4 + 96 + 255) / 256, 256, 0, stream>>>(x, hbx, hb0, hb1, total4, n);

    const int GB = (n + 3) / 4;  // one 64-lane wave per node
    const float inv_n = 1.0f / n;
    float* st0 = gstats + 0 * STATS_PER_LAYER;
    float* st1 = gstats + 1 * STATS_PER_LAYER;
    float* st2 = gstats + 2 * STATS_PER_LAYER;
    float* st3 = gstats + 3 * STATS_PER_LAYER;

    gather_kernel<0><<<GB, 256, 0, stream>>>(hbx, hb0, prowptr, counts, srcsorted,
                                             nullptr, st0, nullptr, nullptr, n, inv_n);
    gather_kernel<1><<<GB, 256, 0, stream>>>(hb0, hb1, prowptr, counts, srcsorted,
                                             st0, st1, gamma + 0 * DIM, beta + 0 * DIM,
                                             n, inv_n);
    gather_kernel<1><<<GB, 256, 0, stream>>>(hb1, hb0, prowptr, counts, srcsorted,
                                             st1, st2, gamma + 1 * DIM, beta + 1 * DIM,
                                             n, inv_n);
    gather_kernel<1><<<GB, 256, 0, stream>>>(hb0, hb1, prowptr, counts, srcsorted,
                                             st2, st3, gamma + 2 * DIM, beta + 2 * DIM,
                                             n, inv_n);
    apply_kernel<<<256, 256, 0, stream>>>(hb1, st3, gamma + 3 * DIM, beta + 3 * DIM, out,
                                          total4, inv_n);
}

// Round 8
// 183.059 us; speedup vs baseline: 5.1892x; 1.1612x over previous
//
#include <hip/hip_runtime.h>

#define DIM 128
#define BN_EPS_F 1e-5f
#define NSLICE 16   // stat slices: spreads atomic contention; preamble reduces them
#define MAXN 10240  // LDS histogram capacity (n = 10000)
#define CHUNKS 256  // edge chunks == blocks in chunkhist/scatter

typedef unsigned int u32;
typedef unsigned short u16;

__device__ __forceinline__ float bflo(u32 w) {
    union { u32 u; float f; } c; c.u = w << 16; return c.f;
}
__device__ __forceinline__ float bfhi(u32 w) {
    union { u32 u; float f; } c; c.u = w & 0xffff0000u; return c.f;
}
// pack two floats to bf16x2 with round-to-nearest-even
__device__ __forceinline__ u32 packbf(float x, float y) {
    union { float f; u32 u; } ax, ay; ax.f = x; ay.f = y;
    u32 xr = (ax.u + 0x7fffu + ((ax.u >> 16) & 1u)) >> 16;
    u32 yr = (ay.u + 0x7fffu + ((ay.u >> 16) & 1u)) >> 16;
    return xr | (yr << 16);
}

// ---------------- CSR build (atomic-free counting sort) ----------------

// A: per-chunk private LDS histogram -> hist[chunk][bin]
__global__ __launch_bounds__(256) void chunkhist_kernel(const int* __restrict__ dst,
                                                        int* __restrict__ hist,
                                                        int n, int E, int chunk) {
    __shared__ int bins[MAXN];
    int tid = threadIdx.x;
    for (int i = tid; i < n; i += 256) bins[i] = 0;
    __syncthreads();
    int e0 = blockIdx.x * chunk;
    int e1 = min(e0 + chunk, E);
    for (int e = e0 + tid; e < e1; e += 256) atomicAdd(&bins[dst[e]], 1);
    __syncthreads();
    int* out = hist + (size_t)blockIdx.x * n;
    for (int i = tid; i < n; i += 256) out[i] = bins[i];
}

// B1: per-bin exclusive prefix over chunks; counts[bin] = total degree
__global__ __launch_bounds__(256) void chunkscan_kernel(const int* __restrict__ hist,
                                                        int* __restrict__ chunkpref,
                                                        int* __restrict__ counts, int n) {
    int bin = blockIdx.x * 256 + threadIdx.x;
    if (bin >= n) return;
    const int* hp = hist + bin;
    int* cp = chunkpref + bin;
    int run = 0;
#pragma unroll 32
    for (int b = 0; b < CHUNKS; b++) {
        int v = hp[(size_t)b * n];
        cp[(size_t)b * n] = run;
        run += v;
    }
    counts[bin] = run;
}

// B2: exclusive scan of 16-PADDED counts -> prowptr (scan only; pads elsewhere)
__global__ __launch_bounds__(1024) void scan_kernel(const int* __restrict__ counts,
                                                    int* __restrict__ prowptr, int n) {
    __shared__ int sums[1024];
    const int CH = 16;
    int t = threadIdx.x;
    int base = t * CH;
    int local[CH];
    int s = 0;
#pragma unroll
    for (int i = 0; i < CH; i++) {
        int idx = base + i;
        local[i] = s;
        if (idx < n) s += (counts[idx] + 15) & ~15;
    }
    sums[t] = s;
    __syncthreads();
    for (int off = 1; off < 1024; off <<= 1) {
        int v = (t >= off) ? sums[t - off] : 0;
        __syncthreads();
        sums[t] += v;
        __syncthreads();
    }
    int prev = (t > 0) ? sums[t - 1] : 0;
#pragma unroll
    for (int i = 0; i < CH; i++) {
        int idx = base + i;
        if (idx < n) prowptr[idx] = prev + local[i];
    }
    if (t == 1023) prowptr[n] = sums[1023];
}

// B3: parallel pad-fill — node i writes its <=15 dummy slots
__global__ __launch_bounds__(256) void pad_kernel(const int* __restrict__ prowptr,
                                                  const int* __restrict__ counts,
                                                  int* __restrict__ srcsorted, int n) {
    int i = blockIdx.x * blockDim.x + threadIdx.x;
    if (i < n) {
        int pstart = prowptr[i];
        int c = counts[i];
        int p = (c + 15) & ~15;
        for (int k = c; k < p; k++) srcsorted[pstart + k] = n;  // dummy -> zero row
    }
}

// C: scatter via LDS-ranked positions (no global atomics)
__global__ __launch_bounds__(256) void scatter_kernel(const int* __restrict__ src,
                                                      const int* __restrict__ dst,
                                                      const int* __restrict__ prowptr,
                                                      const int* __restrict__ chunkpref,
                                                      int* __restrict__ srcsorted,
                                                      int n, int E, int chunk) {
    __shared__ int cur[MAXN];
    int tid = threadIdx.x;
    const int* cp = chunkpref + (size_t)blockIdx.x * n;
    for (int i = tid; i < n; i += 256) cur[i] = prowptr[i] + cp[i];
    __syncthreads();
    int e0 = blockIdx.x * chunk;
    int e1 = min(e0 + chunk, E);
    for (int e = e0 + tid; e < e1; e += 256) {
        int d = dst[e];
        int pos = atomicAdd(&cur[d], 1);
        srcsorted[pos] = src[e];
    }
}

// ---------------- fp32 -> bf16 convert (x table) + zero dummy rows ----------------
__global__ void cvt_kernel(const float* __restrict__ x, u16* __restrict__ xb,
                           u16* __restrict__ r0, u16* __restrict__ r1, int total4, int n) {
    int i = blockIdx.x * blockDim.x + threadIdx.x;
    if (i < total4) {
        float4 v = ((const float4*)x)[i];
        uint2 w;
        w.x = packbf(v.x, v.y);
        w.y = packbf(v.z, v.w);
        *(uint2*)(xb + (size_t)i * 4) = w;
    } else {
        int j = i - total4;
        if (j < 96) {
            u16* t = (j < 32) ? xb : ((j < 64) ? r0 : r1);
            uint2 z; z.x = 0; z.y = 0;
            *(uint2*)(t + (size_t)n * DIM + (j & 31) * 4) = z;
        }
    }
}

// ---------------- fused affine(prev-BN) + GIN aggregate + stats ----------------
// Preamble (USE_AB): every block reduces the PREVIOUS layer's sliced stats and
// computes a,b into LDS (kernel boundary = free device-wide sync; no fences).
// Body: one 64-lane wave per node; lane = grp(4) x sub(16). Each 16-lane group
// reads a FULL 256B bf16 row with one uint4 load -> 4 edges per wave-instr.
// Edge lists are 16-padded with dummy node n (zero row) -> NO tail loop.
// Epilogue: block-reduce rounded outputs, fp32 atomics into THIS layer's slice.
template <int USE_AB>
__global__ __launch_bounds__(256) void gather_kernel(
    const u16* __restrict__ hin, u16* __restrict__ hout,
    const int* __restrict__ prowptr, const int* __restrict__ counts,
    const int* __restrict__ srcs,
    const float* __restrict__ stats_in, float* __restrict__ stats_out,
    const float* __restrict__ gamma, const float* __restrict__ beta,
    int n, float inv_n) {
    __shared__ float ab_s[2 * DIM];
    __shared__ float part[2][DIM];
    __shared__ float ls[4][DIM];
    __shared__ float lq[4][DIM];
    int tid = threadIdx.x;
    int wid = tid >> 6;
    int node = blockIdx.x * 4 + wid;
    int lane = tid & 63;
    int grp = lane >> 4;   // 0..3: which edge-slot
    int sub = lane & 15;   // 16 lanes x uint4 = 256B = one bf16 row

    if (USE_AB) {
        int c = tid & 127;
        int which = tid >> 7;  // 0 = sums, 1 = squares
        const float* basep = stats_in + which * NSLICE * DIM + c;
        float acc = 0.f;
#pragma unroll
        for (int k = 0; k < NSLICE; k++) acc += basep[k * DIM];
        part[which][c] = acc;
        __syncthreads();
        if (tid < DIM) {
            float mu = part[0][tid] * inv_n;
            float var = part[1][tid] * inv_n - mu * mu;
            float av = gamma[tid] * rsqrtf(var + BN_EPS_F);
            ab_s[tid] = av;
            ab_s[DIM + tid] = beta[tid] - mu * av;
        }
        __syncthreads();
    }

    float r[8];
#pragma unroll
    for (int k = 0; k < 8; k++) r[k] = 0.f;

    if (node < n) {
        int start = prowptr[node];
        int pend = prowptr[node + 1];
        int deg = counts[node];
        const u16* hsub = hin + sub * 8;
        float acc[8];
#pragma unroll
        for (int k = 0; k < 8; k++) acc[k] = 0.f;

        for (int eb = start; eb < pend; eb += 16) {
            int e0 = eb + grp * 4;
            int s0 = srcs[e0 + 0];
            int s1 = srcs[e0 + 1];
            int s2 = srcs[e0 + 2];
            int s3 = srcs[e0 + 3];
            uint4 v0 = *(const uint4*)(hsub + (size_t)s0 * DIM);
            uint4 v1 = *(const uint4*)(hsub + (size_t)s1 * DIM);
            uint4 v2 = *(const uint4*)(hsub + (size_t)s2 * DIM);
            uint4 v3 = *(const uint4*)(hsub + (size_t)s3 * DIM);
            acc[0] += (bflo(v0.x) + bflo(v1.x)) + (bflo(v2.x) + bflo(v3.x));
            acc[1] += (bfhi(v0.x) + bfhi(v1.x)) + (bfhi(v2.x) + bfhi(v3.x));
            acc[2] += (bflo(v0.y) + bflo(v1.y)) + (bflo(v2.y) + bflo(v3.y));
            acc[3] += (bfhi(v0.y) + bfhi(v1.y)) + (bfhi(v2.y) + bfhi(v3.y));
            acc[4] += (bflo(v0.z) + bflo(v1.z)) + (bflo(v2.z) + bflo(v3.z));
            acc[5] += (bfhi(v0.z) + bfhi(v1.z)) + (bfhi(v2.z) + bfhi(v3.z));
            acc[6] += (bflo(v0.w) + bflo(v1.w)) + (bflo(v2.w) + bflo(v3.w));
            acc[7] += (bfhi(v0.w) + bfhi(v1.w)) + (bfhi(v2.w) + bfhi(v3.w));
        }
        // reduce the 4 groups: lanes with same sub end up with the full sum
#pragma unroll
        for (int k = 0; k < 8; k++) {
            acc[k] += __shfl_xor(acc[k], 16);
            acc[k] += __shfl_xor(acc[k], 32);
        }

        uint4 sv = *(const uint4*)(hin + (size_t)node * DIM + sub * 8);
        float self[8] = {bflo(sv.x), bfhi(sv.x), bflo(sv.y), bfhi(sv.y),
                         bflo(sv.z), bfhi(sv.z), bflo(sv.w), bfhi(sv.w)};
        float degp1 = 1.0f + (float)deg;

        float av[8], bv[8];
        if (USE_AB) {
            float4 a0 = *(const float4*)(ab_s + sub * 8);
            float4 a1 = *(const float4*)(ab_s + sub * 8 + 4);
            float4 b0 = *(const float4*)(ab_s + DIM + sub * 8);
            float4 b1 = *(const float4*)(ab_s + DIM + sub * 8 + 4);
            av[0] = a0.x; av[1] = a0.y; av[2] = a0.z; av[3] = a0.w;
            av[4] = a1.x; av[5] = a1.y; av[6] = a1.z; av[7] = a1.w;
            bv[0] = b0.x; bv[1] = b0.y; bv[2] = b0.z; bv[3] = b0.w;
            bv[4] = b1.x; bv[5] = b1.y; bv[6] = b1.z; bv[7] = b1.w;
        } else {
#pragma unroll
            for (int k = 0; k < 8; k++) { av[k] = 1.f; bv[k] = 0.f; }
        }

        float o[8];
#pragma unroll
        for (int k = 0; k < 8; k++) o[k] = av[k] * (self[k] + acc[k]) + degp1 * bv[k];
        u32 w0 = packbf(o[0], o[1]);
        u32 w1 = packbf(o[2], o[3]);
        u32 w2 = packbf(o[4], o[5]);
        u32 w3 = packbf(o[6], o[7]);
        if (grp == 0) {
            uint4 wv; wv.x = w0; wv.y = w1; wv.z = w2; wv.w = w3;
            *(uint4*)(hout + (size_t)node * DIM + sub * 8) = wv;
        }
        r[0] = bflo(w0); r[1] = bfhi(w0); r[2] = bflo(w1); r[3] = bfhi(w1);
        r[4] = bflo(w2); r[5] = bfhi(w2); r[6] = bflo(w3); r[7] = bfhi(w3);
    }

    // stats of rounded values (grp 0 holds the final r for its node; zeros if node>=n)
    if (grp == 0) {
#pragma unroll
        for (int k = 0; k < 8; k++) {
            ls[wid][sub * 8 + k] = r[k];
            lq[wid][sub * 8 + k] = r[k] * r[k];
        }
    }
    __syncthreads();
    int slice = (blockIdx.x & (NSLICE - 1)) * DIM;
    int c = tid & 127;
    int which = tid >> 7;
    float s = which ? ((lq[0][c] + lq[1][c]) + (lq[2][c] + lq[3][c]))
                    : ((ls[0][c] + ls[1][c]) + (ls[2][c] + ls[3][c]));
    atomicAdd(&stats_out[which * NSLICE * DIM + slice + c], s);
}

// ---------------- final affine apply (layer 3) ----------------
__global__ __launch_bounds__(256) void apply_kernel(const u16* __restrict__ hb,
                                                    const float* __restrict__ stats_in,
                                                    const float* __restrict__ gamma,
                                                    const float* __restrict__ beta,
                                                    float* __restrict__ out, int total4,
                                                    float inv_n) {
    __shared__ float ab_s[2 * DIM];
    __shared__ float part[2][DIM];
    int tid = threadIdx.x;
    {
        int c = tid & 127;
        int which = tid >> 7;
        const float* basep = stats_in + which * NSLICE * DIM + c;
        float acc = 0.f;
#pragma unroll
        for (int k = 0; k < NSLICE; k++) acc += basep[k * DIM];
        part[which][c] = acc;
        __syncthreads();
        if (tid < DIM) {
            float mu = part[0][tid] * inv_n;
            float var = part[1][tid] * inv_n - mu * mu;
            float av = gamma[tid] * rsqrtf(var + BN_EPS_F);
            ab_s[tid] = av;
            ab_s[DIM + tid] = beta[tid] - mu * av;
        }
        __syncthreads();
    }
    for (int i = blockIdx.x * blockDim.x + tid; i < total4; i += gridDim.x * blockDim.x) {
        int quad = i & 31;
        uint2 w = *(const uint2*)(hb + (size_t)i * 4);
        const float4 a = *(const float4*)(ab_s + quad * 4);
        const float4 b = *(const float4*)(ab_s + DIM + quad * 4);
        float4 r;
        r.x = a.x * bflo(w.x) + b.x;
        r.y = a.y * bfhi(w.x) + b.y;
        r.z = a.z * bflo(w.y) + b.z;
        r.w = a.w * bfhi(w.y) + b.w;
        ((float4*)out)[i] = r;
    }
}

extern "C" void kernel_launch(void* const* d_in, const int* in_sizes, int n_in,
                              void* d_out, int out_size, void* d_ws, size_t ws_size,
                              hipStream_t stream) {
    const float* x = (const float*)d_in[0];
    const float* gamma = (const float*)d_in[1];
    const float* beta = (const float*)d_in[2];
    const int* src = (const int*)d_in[3];
    const int* dst = (const int*)d_in[4];
    float* out = (float*)d_out;

    const int n = in_sizes[0] / DIM;   // 10000
    const int E = in_sizes[3];         // 640000

    char* ws = (char*)d_ws;
    auto alloc = [&](size_t bytes) -> char* {
        char* p = ws;
        ws += (bytes + 255) / 256 * 256;
        return p;
    };
    const int STATS_PER_LAYER = 2 * NSLICE * DIM;                 // sums + squares
    int* prowptr = (int*)alloc((size_t)(n + 1) * 4);
    int* counts = (int*)alloc((size_t)n * 4);
    float* gstats = (float*)alloc((size_t)4 * STATS_PER_LAYER * 4);  // zeroed
    int* hist = (int*)alloc((size_t)CHUNKS * n * 4);
    int* chunkpref = (int*)alloc((size_t)CHUNKS * n * 4);
    int* srcsorted = (int*)alloc((size_t)(E + 16 * n) * 4);       // padded
    u16* hbx = (u16*)alloc((size_t)(n + 1) * DIM * 2);
    u16* hb0 = (u16*)alloc((size_t)(n + 1) * DIM * 2);
    u16* hb1 = (u16*)alloc((size_t)(n + 1) * DIM * 2);

    hipMemsetAsync(gstats, 0, (size_t)4 * STATS_PER_LAYER * 4, stream);

    const int chunk = (E + CHUNKS - 1) / CHUNKS;
    chunkhist_kernel<<<CHUNKS, 256, 0, stream>>>(dst, hist, n, E, chunk);
    chunkscan_kernel<<<(n + 255) / 256, 256, 0, stream>>>(hist, chunkpref, counts, n);
    scan_kernel<<<1, 1024, 0, stream>>>(counts, prowptr, n);
    pad_kernel<<<(n + 255) / 256, 256, 0, stream>>>(prowptr, counts, srcsorted, n);
    scatter_kernel<<<CHUNKS, 256, 0, stream>>>(src, dst, prowptr, chunkpref, srcsorted,
                                               n, E, chunk);
    const int total4 = n * DIM / 4;
    cvt_kernel<<<(total4 + 96 + 255) / 256, 256, 0, stream>>>(x, hbx, hb0, hb1, total4, n);

    const int GB = (n + 3) / 4;  // one 64-lane wave per node
    const float inv_n = 1.0f / n;
    float* st0 = gstats + 0 * STATS_PER_LAYER;
    float* st1 = gstats + 1 * STATS_PER_LAYER;
    float* st2 = gstats + 2 * STATS_PER_LAYER;
    float* st3 = gstats + 3 * STATS_PER_LAYER;

    gather_kernel<0><<<GB, 256, 0, stream>>>(hbx, hb0, prowptr, counts, srcsorted,
                                             nullptr, st0, nullptr, nullptr, n, inv_n);
    gather_kernel<1><<<GB, 256, 0, stream>>>(hb0, hb1, prowptr, counts, srcsorted,
                                             st0, st1, gamma + 0 * DIM, beta + 0 * DIM,
                                             n, inv_n);
    gather_kernel<1><<<GB, 256, 0, stream>>>(hb1, hb0, prowptr, counts, srcsorted,
                                             st1, st2, gamma + 1 * DIM, beta + 1 * DIM,
                                             n, inv_n);
    gather_kernel<1><<<GB, 256, 0, stream>>>(hb0, hb1, prowptr, counts, srcsorted,
                                             st2, st3, gamma + 2 * DIM, beta + 2 * DIM,
                                             n, inv_n);
    apply_kernel<<<256, 256, 0, stream>>>(hb1, st3, gamma + 3 * DIM, beta + 3 * DIM, out,
                                          total4, inv_n);
}

// Round 9
// 180.244 us; speedup vs baseline: 5.2702x; 1.0156x over previous
//
#include <hip/hip_runtime.h>

#define DIM 128
#define BN_EPS_F 1e-5f
#define NSLICE 16   // stat slices: spreads atomic contention; preamble reduces them
#define MAXN 10240  // LDS histogram capacity (n = 10000)
#define CHUNKS 256  // edge chunks == blocks in chunkhist/scatter

typedef unsigned int u32;
typedef unsigned short u16;

__device__ __forceinline__ float bflo(u32 w) {
    union { u32 u; float f; } c; c.u = w << 16; return c.f;
}
__device__ __forceinline__ float bfhi(u32 w) {
    union { u32 u; float f; } c; c.u = w & 0xffff0000u; return c.f;
}
// pack two floats to bf16x2 with round-to-nearest-even
__device__ __forceinline__ u32 packbf(float x, float y) {
    union { float f; u32 u; } ax, ay; ax.f = x; ay.f = y;
    u32 xr = (ax.u + 0x7fffu + ((ax.u >> 16) & 1u)) >> 16;
    u32 yr = (ay.u + 0x7fffu + ((ay.u >> 16) & 1u)) >> 16;
    return xr | (yr << 16);
}

// ---------------- CSR build (atomic-free counting sort) ----------------

// A: per-chunk private LDS histogram -> hist[chunk][bin]
__global__ __launch_bounds__(256) void chunkhist_kernel(const int* __restrict__ dst,
                                                        int* __restrict__ hist,
                                                        int n, int E, int chunk) {
    __shared__ int bins[MAXN];
    int tid = threadIdx.x;
    for (int i = tid; i < n; i += 256) bins[i] = 0;
    __syncthreads();
    int e0 = blockIdx.x * chunk;
    int e1 = min(e0 + chunk, E);
    for (int e = e0 + tid; e < e1; e += 256) atomicAdd(&bins[dst[e]], 1);
    __syncthreads();
    int* out = hist + (size_t)blockIdx.x * n;
    for (int i = tid; i < n; i += 256) out[i] = bins[i];
}

// B1: per-bin exclusive prefix over chunks; counts[bin] = total degree
__global__ __launch_bounds__(256) void chunkscan_kernel(const int* __restrict__ hist,
                                                        int* __restrict__ chunkpref,
                                                        int* __restrict__ counts, int n) {
    int bin = blockIdx.x * 256 + threadIdx.x;
    if (bin >= n) return;
    const int* hp = hist + bin;
    int* cp = chunkpref + bin;
    int run = 0;
#pragma unroll 32
    for (int b = 0; b < CHUNKS; b++) {
        int v = hp[(size_t)b * n];
        cp[(size_t)b * n] = run;
        run += v;
    }
    counts[bin] = run;
}

// B2: exclusive scan of 16-PADDED counts -> prowptr (scan only)
__global__ __launch_bounds__(1024) void scan_kernel(const int* __restrict__ counts,
                                                    int* __restrict__ prowptr, int n) {
    __shared__ int sums[1024];
    const int CH = 16;
    int t = threadIdx.x;
    int base = t * CH;
    int local[CH];
    int s = 0;
#pragma unroll
    for (int i = 0; i < CH; i++) {
        int idx = base + i;
        local[i] = s;
        if (idx < n) s += (counts[idx] + 15) & ~15;
    }
    sums[t] = s;
    __syncthreads();
    for (int off = 1; off < 1024; off <<= 1) {
        int v = (t >= off) ? sums[t - off] : 0;
        __syncthreads();
        sums[t] += v;
        __syncthreads();
    }
    int prev = (t > 0) ? sums[t - 1] : 0;
#pragma unroll
    for (int i = 0; i < CH; i++) {
        int idx = base + i;
        if (idx < n) prowptr[idx] = prev + local[i];
    }
    if (t == 1023) prowptr[n] = sums[1023];
}

// B3: misc fused kernel — cvt x->bf16 (+zero dummy rows), pad-fill, zero gstats
__global__ __launch_bounds__(256) void misc_kernel(const float* __restrict__ x,
                                                   u16* __restrict__ xb,
                                                   u16* __restrict__ r0,
                                                   u16* __restrict__ r1,
                                                   const int* __restrict__ prowptr,
                                                   const int* __restrict__ counts,
                                                   int* __restrict__ srcsorted,
                                                   float* __restrict__ gstats,
                                                   int total4, int n,
                                                   int nb_cvt, int nb_pad, int gtotal) {
    int bid = blockIdx.x;
    int tid = threadIdx.x;
    if (bid < nb_cvt) {
        int i = bid * 256 + tid;
        if (i < total4) {
            float4 v = ((const float4*)x)[i];
            uint2 w;
            w.x = packbf(v.x, v.y);
            w.y = packbf(v.z, v.w);
            *(uint2*)(xb + (size_t)i * 4) = w;
        } else {
            int j = i - total4;
            if (j < 96) {
                u16* t = (j < 32) ? xb : ((j < 64) ? r0 : r1);
                uint2 z; z.x = 0; z.y = 0;
                *(uint2*)(t + (size_t)n * DIM + (j & 31) * 4) = z;
            }
        }
    } else if (bid < nb_cvt + nb_pad) {
        int i = (bid - nb_cvt) * 256 + tid;
        if (i < n) {
            int pstart = prowptr[i];
            int c = counts[i];
            int p = (c + 15) & ~15;
            for (int k = c; k < p; k++) srcsorted[pstart + k] = n;  // dummy -> zero row
        }
    } else {
        int i = (bid - nb_cvt - nb_pad) * 256 + tid;
        if (i < gtotal) gstats[i] = 0.f;
    }
}

// C: scatter via LDS-ranked positions (no global atomics)
__global__ __launch_bounds__(256) void scatter_kernel(const int* __restrict__ src,
                                                      const int* __restrict__ dst,
                                                      const int* __restrict__ prowptr,
                                                      const int* __restrict__ chunkpref,
                                                      int* __restrict__ srcsorted,
                                                      int n, int E, int chunk) {
    __shared__ int cur[MAXN];
    int tid = threadIdx.x;
    const int* cp = chunkpref + (size_t)blockIdx.x * n;
    for (int i = tid; i < n; i += 256) cur[i] = prowptr[i] + cp[i];
    __syncthreads();
    int e0 = blockIdx.x * chunk;
    int e1 = min(e0 + chunk, E);
    for (int e = e0 + tid; e < e1; e += 256) {
        int d = dst[e];
        int pos = atomicAdd(&cur[d], 1);
        srcsorted[pos] = src[e];
    }
}

// ---------------- fused affine(prev-BN) + GIN aggregate + stats ----------------
// Preamble (USE_AB): every block reduces the PREVIOUS layer's sliced stats and
// computes a,b into LDS (kernel boundary = free device-wide sync; no fences).
// Body: one 64-lane wave per node; lane = grp(4) x sub(16). Each 16-lane group
// reads a FULL 256B bf16 row with one uint4 load. Unroll x2 -> 8 independent
// {srcs -> row} chains in flight per wave. Edge lists 16-padded (dummy node n,
// zero row) -> no scalar tail.
// Epilogue: block-reduce rounded outputs, fp32 atomics into THIS layer's slice.
template <int USE_AB>
__global__ __launch_bounds__(256) void gather_kernel(
    const u16* __restrict__ hin, u16* __restrict__ hout,
    const int* __restrict__ prowptr, const int* __restrict__ counts,
    const int* __restrict__ srcs,
    const float* __restrict__ stats_in, float* __restrict__ stats_out,
    const float* __restrict__ gamma, const float* __restrict__ beta,
    int n, float inv_n) {
    __shared__ float ab_s[2 * DIM];
    __shared__ float part[2][DIM];
    __shared__ float ls[4][DIM];
    __shared__ float lq[4][DIM];
    int tid = threadIdx.x;
    int wid = tid >> 6;
    int node = blockIdx.x * 4 + wid;
    int lane = tid & 63;
    int grp = lane >> 4;   // 0..3: which edge-slot
    int sub = lane & 15;   // 16 lanes x uint4 = 256B = one bf16 row

    if (USE_AB) {
        int c = tid & 127;
        int which = tid >> 7;  // 0 = sums, 1 = squares
        const float* basep = stats_in + which * NSLICE * DIM + c;
        float acc = 0.f;
#pragma unroll
        for (int k = 0; k < NSLICE; k++) acc += basep[k * DIM];
        part[which][c] = acc;
        __syncthreads();
        if (tid < DIM) {
            float mu = part[0][tid] * inv_n;
            float var = part[1][tid] * inv_n - mu * mu;
            float av = gamma[tid] * rsqrtf(var + BN_EPS_F);
            ab_s[tid] = av;
            ab_s[DIM + tid] = beta[tid] - mu * av;
        }
        __syncthreads();
    }

    float r[8];
#pragma unroll
    for (int k = 0; k < 8; k++) r[k] = 0.f;

    if (node < n) {
        int start = prowptr[node];
        int pend = prowptr[node + 1];
        int deg = counts[node];
        const u16* hsub = hin + sub * 8;
        float acc[8];
#pragma unroll
        for (int k = 0; k < 8; k++) acc[k] = 0.f;

        int eb = start;
        for (; eb + 32 <= pend; eb += 32) {
            int e0 = eb + grp * 4;
            int s0 = srcs[e0 + 0];
            int s1 = srcs[e0 + 1];
            int s2 = srcs[e0 + 2];
            int s3 = srcs[e0 + 3];
            int s4 = srcs[e0 + 16];
            int s5 = srcs[e0 + 17];
            int s6 = srcs[e0 + 18];
            int s7 = srcs[e0 + 19];
            uint4 v0 = *(const uint4*)(hsub + (size_t)s0 * DIM);
            uint4 v1 = *(const uint4*)(hsub + (size_t)s1 * DIM);
            uint4 v2 = *(const uint4*)(hsub + (size_t)s2 * DIM);
            uint4 v3 = *(const uint4*)(hsub + (size_t)s3 * DIM);
            uint4 v4 = *(const uint4*)(hsub + (size_t)s4 * DIM);
            uint4 v5 = *(const uint4*)(hsub + (size_t)s5 * DIM);
            uint4 v6 = *(const uint4*)(hsub + (size_t)s6 * DIM);
            uint4 v7 = *(const uint4*)(hsub + (size_t)s7 * DIM);
            acc[0] += ((bflo(v0.x) + bflo(v1.x)) + (bflo(v2.x) + bflo(v3.x))) +
                      ((bflo(v4.x) + bflo(v5.x)) + (bflo(v6.x) + bflo(v7.x)));
            acc[1] += ((bfhi(v0.x) + bfhi(v1.x)) + (bfhi(v2.x) + bfhi(v3.x))) +
                      ((bfhi(v4.x) + bfhi(v5.x)) + (bfhi(v6.x) + bfhi(v7.x)));
            acc[2] += ((bflo(v0.y) + bflo(v1.y)) + (bflo(v2.y) + bflo(v3.y))) +
                      ((bflo(v4.y) + bflo(v5.y)) + (bflo(v6.y) + bflo(v7.y)));
            acc[3] += ((bfhi(v0.y) + bfhi(v1.y)) + (bfhi(v2.y) + bfhi(v3.y))) +
                      ((bfhi(v4.y) + bfhi(v5.y)) + (bfhi(v6.y) + bfhi(v7.y)));
            acc[4] += ((bflo(v0.z) + bflo(v1.z)) + (bflo(v2.z) + bflo(v3.z))) +
                      ((bflo(v4.z) + bflo(v5.z)) + (bflo(v6.z) + bflo(v7.z)));
            acc[5] += ((bfhi(v0.z) + bfhi(v1.z)) + (bfhi(v2.z) + bfhi(v3.z))) +
                      ((bfhi(v4.z) + bfhi(v5.z)) + (bfhi(v6.z) + bfhi(v7.z)));
            acc[6] += ((bflo(v0.w) + bflo(v1.w)) + (bflo(v2.w) + bflo(v3.w))) +
                      ((bflo(v4.w) + bflo(v5.w)) + (bflo(v6.w) + bflo(v7.w)));
            acc[7] += ((bfhi(v0.w) + bfhi(v1.w)) + (bfhi(v2.w) + bfhi(v3.w))) +
                      ((bfhi(v4.w) + bfhi(v5.w)) + (bfhi(v6.w) + bfhi(v7.w)));
        }
        if (eb < pend) {  // exactly one 16-edge block remains
            int e0 = eb + grp * 4;
            int s0 = srcs[e0 + 0];
            int s1 = srcs[e0 + 1];
            int s2 = srcs[e0 + 2];
            int s3 = srcs[e0 + 3];
            uint4 v0 = *(const uint4*)(hsub + (size_t)s0 * DIM);
            uint4 v1 = *(const uint4*)(hsub + (size_t)s1 * DIM);
            uint4 v2 = *(const uint4*)(hsub + (size_t)s2 * DIM);
            uint4 v3 = *(const uint4*)(hsub + (size_t)s3 * DIM);
            acc[0] += (bflo(v0.x) + bflo(v1.x)) + (bflo(v2.x) + bflo(v3.x));
            acc[1] += (bfhi(v0.x) + bfhi(v1.x)) + (bfhi(v2.x) + bfhi(v3.x));
            acc[2] += (bflo(v0.y) + bflo(v1.y)) + (bflo(v2.y) + bflo(v3.y));
            acc[3] += (bfhi(v0.y) + bfhi(v1.y)) + (bfhi(v2.y) + bfhi(v3.y));
            acc[4] += (bflo(v0.z) + bflo(v1.z)) + (bflo(v2.z) + bflo(v3.z));
            acc[5] += (bfhi(v0.z) + bfhi(v1.z)) + (bfhi(v2.z) + bfhi(v3.z));
            acc[6] += (bflo(v0.w) + bflo(v1.w)) + (bflo(v2.w) + bflo(v3.w));
            acc[7] += (bfhi(v0.w) + bfhi(v1.w)) + (bfhi(v2.w) + bfhi(v3.w));
        }
        // reduce the 4 groups: lanes with same sub end up with the full sum
#pragma unroll
        for (int k = 0; k < 8; k++) {
            acc[k] += __shfl_xor(acc[k], 16);
            acc[k] += __shfl_xor(acc[k], 32);
        }

        uint4 sv = *(const uint4*)(hin + (size_t)node * DIM + sub * 8);
        float self[8] = {bflo(sv.x), bfhi(sv.x), bflo(sv.y), bfhi(sv.y),
                         bflo(sv.z), bfhi(sv.z), bflo(sv.w), bfhi(sv.w)};
        float degp1 = 1.0f + (float)deg;

        float av[8], bv[8];
        if (USE_AB) {
            float4 a0 = *(const float4*)(ab_s + sub * 8);
            float4 a1 = *(const float4*)(ab_s + sub * 8 + 4);
            float4 b0 = *(const float4*)(ab_s + DIM + sub * 8);
            float4 b1 = *(const float4*)(ab_s + DIM + sub * 8 + 4);
            av[0] = a0.x; av[1] = a0.y; av[2] = a0.z; av[3] = a0.w;
            av[4] = a1.x; av[5] = a1.y; av[6] = a1.z; av[7] = a1.w;
            bv[0] = b0.x; bv[1] = b0.y; bv[2] = b0.z; bv[3] = b0.w;
            bv[4] = b1.x; bv[5] = b1.y; bv[6] = b1.z; bv[7] = b1.w;
        } else {
#pragma unroll
            for (int k = 0; k < 8; k++) { av[k] = 1.f; bv[k] = 0.f; }
        }

        float o[8];
#pragma unroll
        for (int k = 0; k < 8; k++) o[k] = av[k] * (self[k] + acc[k]) + degp1 * bv[k];
        u32 w0 = packbf(o[0], o[1]);
        u32 w1 = packbf(o[2], o[3]);
        u32 w2 = packbf(o[4], o[5]);
        u32 w3 = packbf(o[6], o[7]);
        if (grp == 0) {
            uint4 wv; wv.x = w0; wv.y = w1; wv.z = w2; wv.w = w3;
            *(uint4*)(hout + (size_t)node * DIM + sub * 8) = wv;
        }
        r[0] = bflo(w0); r[1] = bfhi(w0); r[2] = bflo(w1); r[3] = bfhi(w1);
        r[4] = bflo(w2); r[5] = bfhi(w2); r[6] = bflo(w3); r[7] = bfhi(w3);
    }

    // stats of rounded values (grp 0 holds the final r for its node; zeros if node>=n)
    if (grp == 0) {
#pragma unroll
        for (int k = 0; k < 8; k++) {
            ls[wid][sub * 8 + k] = r[k];
            lq[wid][sub * 8 + k] = r[k] * r[k];
        }
    }
    __syncthreads();
    int slice = (blockIdx.x & (NSLICE - 1)) * DIM;
    int c = tid & 127;
    int which = tid >> 7;
    float s = which ? ((lq[0][c] + lq[1][c]) + (lq[2][c] + lq[3][c]))
                    : ((ls[0][c] + ls[1][c]) + (ls[2][c] + ls[3][c]));
    atomicAdd(&stats_out[which * NSLICE * DIM + slice + c], s);
}

// ---------------- final affine apply (layer 3) ----------------
__global__ __launch_bounds__(256) void apply_kernel(const u16* __restrict__ hb,
                                                    const float* __restrict__ stats_in,
                                                    const float* __restrict__ gamma,
                                                    const float* __restrict__ beta,
                                                    float* __restrict__ out, int total4,
                                                    float inv_n) {
    __shared__ float ab_s[2 * DIM];
    __shared__ float part[2][DIM];
    int tid = threadIdx.x;
    {
        int c = tid & 127;
        int which = tid >> 7;
        const float* basep = stats_in + which * NSLICE * DIM + c;
        float acc = 0.f;
#pragma unroll
        for (int k = 0; k < NSLICE; k++) acc += basep[k * DIM];
        part[which][c] = acc;
        __syncthreads();
        if (tid < DIM) {
            float mu = part[0][tid] * inv_n;
            float var = part[1][tid] * inv_n - mu * mu;
            float av = gamma[tid] * rsqrtf(var + BN_EPS_F);
            ab_s[tid] = av;
            ab_s[DIM + tid] = beta[tid] - mu * av;
        }
        __syncthreads();
    }
    for (int i = blockIdx.x * blockDim.x + tid; i < total4; i += gridDim.x * blockDim.x) {
        int quad = i & 31;
        uint2 w = *(const uint2*)(hb + (size_t)i * 4);
        const float4 a = *(const float4*)(ab_s + quad * 4);
        const float4 b = *(const float4*)(ab_s + DIM + quad * 4);
        float4 r;
        r.x = a.x * bflo(w.x) + b.x;
        r.y = a.y * bfhi(w.x) + b.y;
        r.z = a.z * bflo(w.y) + b.z;
        r.w = a.w * bfhi(w.y) + b.w;
        ((float4*)out)[i] = r;
    }
}

extern "C" void kernel_launch(void* const* d_in, const int* in_sizes, int n_in,
                              void* d_out, int out_size, void* d_ws, size_t ws_size,
                              hipStream_t stream) {
    const float* x = (const float*)d_in[0];
    const float* gamma = (const float*)d_in[1];
    const float* beta = (const float*)d_in[2];
    const int* src = (const int*)d_in[3];
    const int* dst = (const int*)d_in[4];
    float* out = (float*)d_out;

    const int n = in_sizes[0] / DIM;   // 10000
    const int E = in_sizes[3];         // 640000

    char* ws = (char*)d_ws;
    auto alloc = [&](size_t bytes) -> char* {
        char* p = ws;
        ws += (bytes + 255) / 256 * 256;
        return p;
    };
    const int STATS_PER_LAYER = 2 * NSLICE * DIM;                 // sums + squares
    int* prowptr = (int*)alloc((size_t)(n + 1) * 4);
    int* counts = (int*)alloc((size_t)n * 4);
    float* gstats = (float*)alloc((size_t)4 * STATS_PER_LAYER * 4);
    int* hist = (int*)alloc((size_t)CHUNKS * n * 4);
    int* chunkpref = (int*)alloc((size_t)CHUNKS * n * 4);
    int* srcsorted = (int*)alloc((size_t)(E + 16 * n) * 4);       // padded
    u16* hbx = (u16*)alloc((size_t)(n + 1) * DIM * 2);
    u16* hb0 = (u16*)alloc((size_t)(n + 1) * DIM * 2);
    u16* hb1 = (u16*)alloc((size_t)(n + 1) * DIM * 2);

    const int chunk = (E + CHUNKS - 1) / CHUNKS;
    const int total4 = n * DIM / 4;
    const int gtotal = 4 * STATS_PER_LAYER;
    const int NB_CVT = (total4 + 96 + 255) / 256;
    const int NB_PAD = (n + 255) / 256;
    const int NB_GZ = (gtotal + 255) / 256;

    chunkhist_kernel<<<CHUNKS, 256, 0, stream>>>(dst, hist, n, E, chunk);
    chunkscan_kernel<<<(n + 255) / 256, 256, 0, stream>>>(hist, chunkpref, counts, n);
    scan_kernel<<<1, 1024, 0, stream>>>(counts, prowptr, n);
    misc_kernel<<<NB_CVT + NB_PAD + NB_GZ, 256, 0, stream>>>(x, hbx, hb0, hb1, prowptr,
                                                             counts, srcsorted, gstats,
                                                             total4, n, NB_CVT, NB_PAD,
                                                             gtotal);
    scatter_kernel<<<CHUNKS, 256, 0, stream>>>(src, dst, prowptr, chunkpref, srcsorted,
                                               n, E, chunk);

    const int GB = (n + 3) / 4;  // one 64-lane wave per node
    const float inv_n = 1.0f / n;
    float* st0 = gstats + 0 * STATS_PER_LAYER;
    float* st1 = gstats + 1 * STATS_PER_LAYER;
    float* st2 = gstats + 2 * STATS_PER_LAYER;
    float* st3 = gstats + 3 * STATS_PER_LAYER;

    gather_kernel<0><<<GB, 256, 0, stream>>>(hbx, hb0, prowptr, counts, srcsorted,
                                             nullptr, st0, nullptr, nullptr, n, inv_n);
    gather_kernel<1><<<GB, 256, 0, stream>>>(hb0, hb1, prowptr, counts, srcsorted,
                                             st0, st1, gamma + 0 * DIM, beta + 0 * DIM,
                                             n, inv_n);
    gather_kernel<1><<<GB, 256, 0, stream>>>(hb1, hb0, prowptr, counts, srcsorted,
                                             st1, st2, gamma + 1 * DIM, beta + 1 * DIM,
                                             n, inv_n);
    gather_kernel<1><<<GB, 256, 0, stream>>>(hb0, hb1, prowptr, counts, srcsorted,
                                             st2, st3, gamma + 2 * DIM, beta + 2 * DIM,
                                             n, inv_n);
    apply_kernel<<<256, 256, 0, stream>>>(hb1, st3, gamma + 3 * DIM, beta + 3 * DIM, out,
                                          total4, inv_n);
}